// Round 5
// baseline (1398.406 us; speedup 1.0000x reference)
//
#include <hip/hip_runtime.h>
#include <cstdint>
#include <cstddef>

// ---------------------------------------------------------------------------
// RestrictedTransformerEncoderLayer on MI355X (gfx950)  — ROUND 5
// B=2, L=2048, E=1024, H=16, D=64, FF=4096, WIN=128.
// External I/O: float32 (per reference — confirmed by r2 vs r3/4 bisect).
// Internal intermediates: bf16 (MFMA). Output: f32 into d_out.
// Workspace (peak 40 MB):
//   qkv  bf16 [0,        25165824)   dead after attn
//   ctx  bf16 [25165824, 33554432)   dead after out-proj
//   attnb bf16[33554432, 41943040)   dead after LN1
//   x1b  bf16 [0,         8388608)   (reuses qkv)   live until LN2
//   ff1  bf16 [8388608,  41943040)   (reuses ctx+attnb)
//   ff2  f32  -> d_out (16 MB), LN2 in-place per-row
// ---------------------------------------------------------------------------

typedef __attribute__((ext_vector_type(8))) short short8;   // 8 x bf16 MFMA frag
typedef __attribute__((ext_vector_type(4))) float f32x4;    // MFMA accumulator

__device__ __forceinline__ float b2f(unsigned short u) {
  union { unsigned int i; float f; } x; x.i = ((unsigned int)u) << 16; return x.f;
}
__device__ __forceinline__ unsigned short f2b(float f) {
  union { float f; unsigned int i; } x; x.f = f;
  unsigned int i = x.i;
  unsigned int r = (i + 0x7FFFu + ((i >> 16) & 1u)) >> 16;  // RNE
  return (unsigned short)r;
}
__device__ __forceinline__ uint4 pack8(float4 f0, float4 f1) {
  uint4 r;
  r.x = (unsigned)f2b(f0.x) | ((unsigned)f2b(f0.y) << 16);
  r.y = (unsigned)f2b(f0.z) | ((unsigned)f2b(f0.w) << 16);
  r.z = (unsigned)f2b(f1.x) | ((unsigned)f2b(f1.y) << 16);
  r.w = (unsigned)f2b(f1.z) | ((unsigned)f2b(f1.w) << 16);
  return r;
}

// ---------------------------------------------------------------------------
// GEMM: out[M,N] = A[M,K] @ W[N,K]^T + bias.  W/bias external f32.
// AF32: A is external f32 (convert on stage) else internal bf16.
// OUT32: store f32 (else bf16).  RELU: max(0,.) in epilogue.
// 64x64 tile, BK=32, 256 threads = 4 waves 2x2, wave does 32x32 (4 MFMAs).
// MFMA usage verified correct by r3==r4 cross-implementation agreement.
// ---------------------------------------------------------------------------
template<int RELU, int AF32, int OUT32>
__global__ __launch_bounds__(256) void gemm_bt(
    const void* __restrict__ Av, const float* __restrict__ W,
    const float* __restrict__ bias, void* __restrict__ out,
    int M, int N, int K)
{
  // LDS row stride 40 bf16 = 80 B: 16B-aligned rows, 2-way bank alias (free)
  __shared__ unsigned short As[64 * 40];
  __shared__ unsigned short Bs[64 * 40];

  const int tid = threadIdx.x;
  const int m0 = blockIdx.y * 64, n0 = blockIdx.x * 64;

  const int srow = tid >> 2, skc = tid & 3;    // thread stages 8 elems/operand/step
  size_t aoff = (size_t)(m0 + srow) * K + skc * 8;
  size_t boff = (size_t)(n0 + srow) * K + skc * 8;
  const unsigned short* A16 = (const unsigned short*)Av;
  const float*          A32 = (const float*)Av;
  const int ldst = srow * 40 + skc * 8;

  const int lane = tid & 63, wid = tid >> 6;
  const int msub = (wid >> 1) * 32, nsub = (wid & 1) * 32;
  const int kq = (lane >> 4) * 8;
  const int ar0 = (msub + (lane & 15)) * 40 + kq;
  const int br0 = (nsub + (lane & 15)) * 40 + kq;

  f32x4 acc[2][2];
#pragma unroll
  for (int i = 0; i < 2; ++i)
#pragma unroll
    for (int j = 0; j < 2; ++j) acc[i][j] = (f32x4){0.f, 0.f, 0.f, 0.f};

  const int steps = K >> 5;
  for (int s = 0; s < steps; ++s) {
    uint4 av, bv;
    if (AF32) {
      const float4 f0 = *(const float4*)(A32 + aoff);
      const float4 f1 = *(const float4*)(A32 + aoff + 4);
      av = pack8(f0, f1);
    } else {
      av = *(const uint4*)(A16 + aoff);
    }
    {
      const float4 f0 = *(const float4*)(W + boff);
      const float4 f1 = *(const float4*)(W + boff + 4);
      bv = pack8(f0, f1);
    }
    aoff += 32; boff += 32;
    *(uint4*)&As[ldst] = av;
    *(uint4*)&Bs[ldst] = bv;
    __syncthreads();
    short8 a0 = *(const short8*)&As[ar0];
    short8 a1 = *(const short8*)&As[ar0 + 16 * 40];
    short8 b0 = *(const short8*)&Bs[br0];
    short8 b1 = *(const short8*)&Bs[br0 + 16 * 40];
    acc[0][0] = __builtin_amdgcn_mfma_f32_16x16x32_bf16(a0, b0, acc[0][0], 0, 0, 0);
    acc[0][1] = __builtin_amdgcn_mfma_f32_16x16x32_bf16(a0, b1, acc[0][1], 0, 0, 0);
    acc[1][0] = __builtin_amdgcn_mfma_f32_16x16x32_bf16(a1, b0, acc[1][0], 0, 0, 0);
    acc[1][1] = __builtin_amdgcn_mfma_f32_16x16x32_bf16(a1, b1, acc[1][1], 0, 0, 0);
    __syncthreads();
  }

  // epilogue: D lane mapping col = lane&15, row = (lane>>4)*4 + r  [m89-verified]
#pragma unroll
  for (int nt = 0; nt < 2; ++nt) {
    const int col = n0 + nsub + nt * 16 + (lane & 15);
    const float bvs = bias[col];
#pragma unroll
    for (int mt = 0; mt < 2; ++mt) {
#pragma unroll
      for (int r = 0; r < 4; ++r) {
        const int grow = m0 + msub + mt * 16 + (lane >> 4) * 4 + r;
        float v = acc[mt][nt][r] + bvs;
        if (RELU) v = fmaxf(v, 0.f);
        if (OUT32) ((float*)out)[(size_t)grow * N + col] = v;
        else       ((unsigned short*)out)[(size_t)grow * N + col] = f2b(v);
      }
    }
  }
}

// ---------------------------------------------------------------------------
// Banded attention: softmax(QK^T/8, band |i-j|<=128) @ V per (b, h, 64-query
// tile). Window <= 320 keys in LDS (stride 66 shorts). qkv internal bf16.
// ---------------------------------------------------------------------------
__global__ __launch_bounds__(256) void attn_k(
    const unsigned short* __restrict__ qkv, unsigned short* __restrict__ ctx)
{
  __shared__ unsigned short Ks[320 * 66];
  __shared__ unsigned short Vs[320 * 66];
  __shared__ unsigned short Qs[64 * 66];
  __shared__ float ps[4][320];

  const int tid = threadIdx.x;
  const int bid = blockIdx.x;
  const int qt = bid & 31, h = (bid >> 5) & 15, b = bid >> 9;
  const int q0 = qt * 64;
  const int wstart = max(0, q0 - 128);
  const int wend = min(2048, q0 + 64 + 128);
  const int wc = wend - wstart;                 // 192..320
  const size_t rowb = (size_t)b * 2048;

  for (int idx = tid; idx < wc * 8; idx += 256) {
    const int r = idx >> 3, c = idx & 7;
    const size_t base = (rowb + wstart + r) * 3072 + h * 64 + c * 8;
    const uint4 kv = *(const uint4*)(qkv + base + 1024);
    const uint4 vv = *(const uint4*)(qkv + base + 2048);
    unsigned int* kd = (unsigned int*)&Ks[r * 66 + c * 8];
    unsigned int* vd = (unsigned int*)&Vs[r * 66 + c * 8];
    kd[0] = kv.x; kd[1] = kv.y; kd[2] = kv.z; kd[3] = kv.w;
    vd[0] = vv.x; vd[1] = vv.y; vd[2] = vv.z; vd[3] = vv.w;
  }
  for (int idx = tid; idx < 64 * 8; idx += 256) {
    const int r = idx >> 3, c = idx & 7;
    const uint4 qv = *(const uint4*)(qkv + (rowb + q0 + r) * 3072 + h * 64 + c * 8);
    unsigned int* qd = (unsigned int*)&Qs[r * 66 + c * 8];
    qd[0] = qv.x; qd[1] = qv.y; qd[2] = qv.z; qd[3] = qv.w;
  }
  __syncthreads();

  const int lane = tid & 63, wid = tid >> 6;
  float* psw = ps[wid];

  for (int t16 = 0; t16 < 16; ++t16) {          // uniform trip count
    const int qi = wid * 16 + t16;
    const int i = q0 + qi;
    const int lo = max(0, i - 128) - wstart;
    const int hi = min(2047, i + 128) - wstart;  // inclusive

    unsigned int qreg[32];
    const unsigned int* qrow = (const unsigned int*)&Qs[qi * 66];
#pragma unroll
    for (int dd = 0; dd < 32; ++dd) qreg[dd] = qrow[dd];

    float sc[5];
#pragma unroll
    for (int t = 0; t < 5; ++t) {
      const int j = lane + t * 64;
      float s = 0.f;
      const unsigned int* krow = (const unsigned int*)&Ks[j * 66];
#pragma unroll 8
      for (int dd = 0; dd < 32; ++dd) {
        const unsigned int ku = krow[dd], qu = qreg[dd];
        union { unsigned int i; float f; } k0, k1, ql, qh;
        k0.i = ku << 16; k1.i = ku & 0xffff0000u;
        ql.i = qu << 16; qh.i = qu & 0xffff0000u;
        s += k0.f * ql.f + k1.f * qh.f;
      }
      s *= 0.125f;                               // 1/sqrt(64)
      sc[t] = ((j >= lo) && (j <= hi)) ? s : -1.0e30f;  // select kills any NaN
    }
    float gmax = fmaxf(fmaxf(fmaxf(sc[0], sc[1]), fmaxf(sc[2], sc[3])), sc[4]);
    for (int o = 1; o < 64; o <<= 1) gmax = fmaxf(gmax, __shfl_xor(gmax, o, 64));

    float lsum = 0.f;
#pragma unroll
    for (int t = 0; t < 5; ++t) {
      const int j = lane + t * 64;
      const float p = __expf(sc[t] - gmax);      // exact 0 for masked
      lsum += p;
      psw[j] = p;
    }
    float gsum = lsum;
    for (int o = 1; o < 64; o <<= 1) gsum += __shfl_xor(gsum, o, 64);
    __syncthreads();

    float a = 0.f;
    for (int j = lo; j <= hi; ++j) a += psw[j] * b2f(Vs[j * 66 + lane]);
    a *= 1.0f / gsum;
    ctx[(rowb + i) * 1024 + h * 64 + lane] = f2b(a);
    __syncthreads();
  }
}

// ---------------------------------------------------------------------------
// Residual + LayerNorm over E=1024: o = LN(a + b) * g + be.  g/be f32.
// AF32/BF32/OF32 select dtypes. One block per row; in-place safe when o==a
// or o==b with same dtype (per-row, reads complete before writes).
// ---------------------------------------------------------------------------
template<int AF32, int BF32, int OF32>
__global__ __launch_bounds__(256) void ln_k(
    const void* __restrict__ a, const void* __restrict__ b,
    const float* __restrict__ g, const float* __restrict__ be,
    void* __restrict__ o)
{
  __shared__ float rbuf[8];
  const int tid = threadIdx.x;
  const size_t base = (size_t)blockIdx.x * 1024;
  const int lane = tid & 63, wid = tid >> 6;

  float xv[4], s = 0.f, sq = 0.f;
#pragma unroll
  for (int t = 0; t < 4; ++t) {
    const int c = tid + t * 256;
    const float av = AF32 ? ((const float*)a)[base + c]
                          : b2f(((const unsigned short*)a)[base + c]);
    const float bv = BF32 ? ((const float*)b)[base + c]
                          : b2f(((const unsigned short*)b)[base + c]);
    const float x = av + bv;
    xv[t] = x; s += x; sq += x * x;
  }
  for (int o2 = 1; o2 < 64; o2 <<= 1) { s += __shfl_xor(s, o2, 64); sq += __shfl_xor(sq, o2, 64); }
  if (lane == 0) { rbuf[wid] = s; rbuf[wid + 4] = sq; }
  __syncthreads();
  s  = rbuf[0] + rbuf[1] + rbuf[2] + rbuf[3];
  sq = rbuf[4] + rbuf[5] + rbuf[6] + rbuf[7];
  const float mean = s * (1.0f / 1024.f);
  const float var = sq * (1.0f / 1024.f) - mean * mean;
  const float rstd = rsqrtf(var + 1e-5f);
#pragma unroll
  for (int t = 0; t < 4; ++t) {
    const int c = tid + t * 256;
    const float y = (xv[t] - mean) * rstd * g[c] + be[c];
    if (OF32) ((float*)o)[base + c] = y;
    else      ((unsigned short*)o)[base + c] = f2b(y);
  }
}

// ---------------------------------------------------------------------------
extern "C" void kernel_launch(void* const* d_in, const int* in_sizes, int n_in,
                              void* d_out, int out_size, void* d_ws, size_t ws_size,
                              hipStream_t stream)
{
  (void)in_sizes; (void)n_in; (void)out_size; (void)ws_size;
  const float* src   = (const float*)d_in[0];
  const float* w_in  = (const float*)d_in[1];
  const float* b_in  = (const float*)d_in[2];
  const float* w_out = (const float*)d_in[3];
  const float* b_out = (const float*)d_in[4];
  const float* w1    = (const float*)d_in[5];
  const float* b1    = (const float*)d_in[6];
  const float* w2    = (const float*)d_in[7];
  const float* b2    = (const float*)d_in[8];
  const float* g1    = (const float*)d_in[9];
  const float* be1   = (const float*)d_in[10];
  const float* g2    = (const float*)d_in[11];
  const float* be2   = (const float*)d_in[12];

  char* ws = (char*)d_ws;
  unsigned short* qkv   = (unsigned short*)(ws);                 // [0, 25165824)
  unsigned short* ctx   = (unsigned short*)(ws + 25165824);      // [25165824, 33554432)
  unsigned short* attnb = (unsigned short*)(ws + 33554432);      // [33554432, 41943040)
  unsigned short* x1b   = (unsigned short*)(ws);                 // reuse qkv [0, 8388608)
  unsigned short* ff1   = (unsigned short*)(ws + 8388608);       // [8388608, 41943040)
  float*          outf  = (float*)d_out;                         // ff2 + final (16 MB)

  // 1) QKV projection: [4096,1024] @ [3072,1024]^T -> bf16 qkv
  gemm_bt<0, 1, 0><<<dim3(48, 64), 256, 0, stream>>>(src, w_in, b_in, qkv, 4096, 3072, 1024);
  // 2) banded attention -> bf16 ctx
  attn_k<<<dim3(1024), 256, 0, stream>>>(qkv, ctx);
  // 3) output projection -> bf16 attnb
  gemm_bt<0, 0, 0><<<dim3(16, 64), 256, 0, stream>>>(ctx, w_out, b_out, attnb, 4096, 1024, 1024);
  // 4) LN1(src f32 + attnb bf16) -> bf16 x1b
  ln_k<1, 0, 0><<<dim3(4096), 256, 0, stream>>>(src, attnb, g1, be1, x1b);
  // 5) FF1 + ReLU: [4096,1024] @ [4096,1024]^T -> bf16 ff1
  gemm_bt<1, 0, 0><<<dim3(64, 64), 256, 0, stream>>>(x1b, w1, b1, ff1, 4096, 4096, 1024);
  // 6) FF2: [4096,4096] @ [1024,4096]^T -> f32 into d_out
  gemm_bt<0, 0, 1><<<dim3(16, 64), 256, 0, stream>>>(ff1, w2, b2, outf, 4096, 1024, 4096);
  // 7) LN2(x1b bf16 + d_out f32) -> f32 d_out (in-place, per-row safe)
  ln_k<0, 1, 1><<<dim3(4096), 256, 0, stream>>>(x1b, outf, g2, be2, outf);
}

// Round 6
// 456.445 us; speedup vs baseline: 3.0637x; 3.0637x over previous
//
#include <hip/hip_runtime.h>
#include <cstdint>
#include <cstddef>

// ---------------------------------------------------------------------------
// RestrictedTransformerEncoderLayer on MI355X (gfx950)  — ROUND 6
// B=2, L=2048, E=1024, H=16, D=64, FF=4096, WIN=128.
// External I/O f32; intermediates bf16; output f32.
// R6: attention rewritten as MFMA flash-style (was 1022us VALU/LDS-serial,
// 96KB LDS -> 1 block/CU). Now 27.6KB LDS, 16 MFMA per wave per K-tile.
// Workspace (peak 40 MB): qkv[0,25.2M) ctx[25.2,33.6M) attnb[33.6,41.9M)
//   x1b[0,8.4M) ff1[8.4,41.9M) ; ff2+out in d_out (LN2 in-place).
// ---------------------------------------------------------------------------

typedef __attribute__((ext_vector_type(8))) short short8;   // 8 x bf16 MFMA frag
typedef __attribute__((ext_vector_type(4))) float f32x4;    // MFMA accumulator

__device__ __forceinline__ float b2f(unsigned short u) {
  union { unsigned int i; float f; } x; x.i = ((unsigned int)u) << 16; return x.f;
}
__device__ __forceinline__ unsigned short f2b(float f) {
  union { float f; unsigned int i; } x; x.f = f;
  unsigned int i = x.i;
  unsigned int r = (i + 0x7FFFu + ((i >> 16) & 1u)) >> 16;  // RNE
  return (unsigned short)r;
}
__device__ __forceinline__ uint4 pack8(float4 f0, float4 f1) {
  uint4 r;
  r.x = (unsigned)f2b(f0.x) | ((unsigned)f2b(f0.y) << 16);
  r.y = (unsigned)f2b(f0.z) | ((unsigned)f2b(f0.w) << 16);
  r.z = (unsigned)f2b(f1.x) | ((unsigned)f2b(f1.y) << 16);
  r.w = (unsigned)f2b(f1.z) | ((unsigned)f2b(f1.w) << 16);
  return r;
}

// ---------------------------------------------------------------------------
// GEMM (unchanged from passing r5): out[M,N] = A[M,K] @ W[N,K]^T + bias.
// ---------------------------------------------------------------------------
template<int RELU, int AF32, int OUT32>
__global__ __launch_bounds__(256) void gemm_bt(
    const void* __restrict__ Av, const float* __restrict__ W,
    const float* __restrict__ bias, void* __restrict__ out,
    int M, int N, int K)
{
  __shared__ unsigned short As[64 * 40];
  __shared__ unsigned short Bs[64 * 40];

  const int tid = threadIdx.x;
  const int m0 = blockIdx.y * 64, n0 = blockIdx.x * 64;

  const int srow = tid >> 2, skc = tid & 3;
  size_t aoff = (size_t)(m0 + srow) * K + skc * 8;
  size_t boff = (size_t)(n0 + srow) * K + skc * 8;
  const unsigned short* A16 = (const unsigned short*)Av;
  const float*          A32 = (const float*)Av;
  const int ldst = srow * 40 + skc * 8;

  const int lane = tid & 63, wid = tid >> 6;
  const int msub = (wid >> 1) * 32, nsub = (wid & 1) * 32;
  const int kq = (lane >> 4) * 8;
  const int ar0 = (msub + (lane & 15)) * 40 + kq;
  const int br0 = (nsub + (lane & 15)) * 40 + kq;

  f32x4 acc[2][2];
#pragma unroll
  for (int i = 0; i < 2; ++i)
#pragma unroll
    for (int j = 0; j < 2; ++j) acc[i][j] = (f32x4){0.f, 0.f, 0.f, 0.f};

  const int steps = K >> 5;
  for (int s = 0; s < steps; ++s) {
    uint4 av, bv;
    if (AF32) {
      const float4 f0 = *(const float4*)(A32 + aoff);
      const float4 f1 = *(const float4*)(A32 + aoff + 4);
      av = pack8(f0, f1);
    } else {
      av = *(const uint4*)(A16 + aoff);
    }
    {
      const float4 f0 = *(const float4*)(W + boff);
      const float4 f1 = *(const float4*)(W + boff + 4);
      bv = pack8(f0, f1);
    }
    aoff += 32; boff += 32;
    *(uint4*)&As[ldst] = av;
    *(uint4*)&Bs[ldst] = bv;
    __syncthreads();
    short8 a0 = *(const short8*)&As[ar0];
    short8 a1 = *(const short8*)&As[ar0 + 16 * 40];
    short8 b0 = *(const short8*)&Bs[br0];
    short8 b1 = *(const short8*)&Bs[br0 + 16 * 40];
    acc[0][0] = __builtin_amdgcn_mfma_f32_16x16x32_bf16(a0, b0, acc[0][0], 0, 0, 0);
    acc[0][1] = __builtin_amdgcn_mfma_f32_16x16x32_bf16(a0, b1, acc[0][1], 0, 0, 0);
    acc[1][0] = __builtin_amdgcn_mfma_f32_16x16x32_bf16(a1, b0, acc[1][0], 0, 0, 0);
    acc[1][1] = __builtin_amdgcn_mfma_f32_16x16x32_bf16(a1, b1, acc[1][1], 0, 0, 0);
    __syncthreads();
  }

#pragma unroll
  for (int nt = 0; nt < 2; ++nt) {
    const int col = n0 + nsub + nt * 16 + (lane & 15);
    const float bvs = bias[col];
#pragma unroll
    for (int mt = 0; mt < 2; ++mt) {
#pragma unroll
      for (int r = 0; r < 4; ++r) {
        const int grow = m0 + msub + mt * 16 + (lane >> 4) * 4 + r;
        float v = acc[mt][nt][r] + bvs;
        if (RELU) v = fmaxf(v, 0.f);
        if (OUT32) ((float*)out)[(size_t)grow * N + col] = v;
        else       ((unsigned short*)out)[(size_t)grow * N + col] = f2b(v);
      }
    }
  }
}

// ---------------------------------------------------------------------------
// MFMA flash attention: per (b, h, 64-q tile). 4 waves; wave w owns q rows
// [q0+16w, +16). Iterate K-tiles of 64 keys over the band window
// [max(0,q0-128), min(2048,q0+192)): S=Q@K^T (mfma) -> online softmax
// (per-row state in regs, shfl over 16-lane groups) -> P via LDS (C-layout
// -> A-layout) -> O += P@V (mfma, V staged transposed as B-operand).
// LDS stride 72 shorts: 16B-aligned rows, 2-way bank alias on b128 (free).
// ---------------------------------------------------------------------------
__global__ __launch_bounds__(256) void attn_mfma(
    const unsigned short* __restrict__ qkv, unsigned short* __restrict__ ctx)
{
  __shared__ unsigned short Ks[64 * 72];   // [j][d]
  __shared__ unsigned short Vt[64 * 72];   // [d][j]  (transposed V)
  __shared__ unsigned short Ps[64 * 72];   // [q][j]  (4 waves x 16 rows)

  const int tid = threadIdx.x;
  const int bid = blockIdx.x;
  const int qt = bid & 31, h = (bid >> 5) & 15, b = bid >> 9;
  const int q0 = qt * 64;
  const int wstart = max(0, q0 - 128);
  const int wend = min(2048, q0 + 64 + 128);
  const int ntile = (wend - wstart + 63) >> 6;   // 3..5, uniform per block
  const size_t rowb = (size_t)b * 2048;

  const int lane = tid & 63, wid = tid >> 6;
  const int cl = lane & 15;          // col-within-16 / A-row index
  const int kq = (lane >> 4) * 8;    // k sub-offset per 16-lane group
  const int rowg = lane >> 4;        // row group: rows rowg*4 + r

  // Q A-frags direct from global (row = q0 + wid*16 + cl, k = kq + 32*ks)
  short8 aQ[2];
#pragma unroll
  for (int ks = 0; ks < 2; ++ks)
    aQ[ks] = *(const short8*)(qkv + (rowb + q0 + wid * 16 + cl) * 3072 + h * 64 + ks * 32 + kq);

  float m_i[4], l_i[4];
  f32x4 O[4];
#pragma unroll
  for (int r = 0; r < 4; ++r) { m_i[r] = -1.0e30f; l_i[r] = 0.f; }
#pragma unroll
  for (int nt = 0; nt < 4; ++nt) O[nt] = (f32x4){0.f, 0.f, 0.f, 0.f};

  for (int t = 0; t < ntile; ++t) {
    const int jbase = wstart + t * 64;
    __syncthreads();                            // prev tile's compute done
    // stage K tile (row-major) and V tile (transposed); zero-fill past wend
    for (int idx = tid; idx < 512; idx += 256) {
      const int r = idx >> 3, c = idx & 7;
      const int jg = jbase + r;
      uint4 kv = {0u, 0u, 0u, 0u}, vv = {0u, 0u, 0u, 0u};
      if (jg < wend) {
        const size_t base = (rowb + jg) * 3072 + h * 64 + c * 8;
        kv = *(const uint4*)(qkv + base + 1024);
        vv = *(const uint4*)(qkv + base + 2048);
      }
      *(uint4*)&Ks[r * 72 + c * 8] = kv;
      const unsigned short* vs = (const unsigned short*)&vv;
#pragma unroll
      for (int ii = 0; ii < 8; ++ii) Vt[(c * 8 + ii) * 72 + r] = vs[ii];
    }
    __syncthreads();

    // S = Q @ K^T  (16 q-rows x 64 j), 4 col-tiles x 2 k-steps
    f32x4 S[4];
#pragma unroll
    for (int nt = 0; nt < 4; ++nt) S[nt] = (f32x4){0.f, 0.f, 0.f, 0.f};
#pragma unroll
    for (int nt = 0; nt < 4; ++nt)
#pragma unroll
      for (int ks = 0; ks < 2; ++ks) {
        const short8 bK = *(const short8*)&Ks[(nt * 16 + cl) * 72 + ks * 32 + kq];
        S[nt] = __builtin_amdgcn_mfma_f32_16x16x32_bf16(aQ[ks], bK, S[nt], 0, 0, 0);
      }

    // scale + band mask (C-layout: col = nt*16+cl, row = rowg*4+r)
    float sc[4][4];
#pragma unroll
    for (int nt = 0; nt < 4; ++nt) {
      const int jg = jbase + nt * 16 + cl;
#pragma unroll
      for (int r = 0; r < 4; ++r) {
        const int i = q0 + wid * 16 + rowg * 4 + r;
        const bool v = (jg < wend) && (jg >= i - 128) && (jg <= i + 128);
        sc[nt][r] = v ? S[nt][r] * 0.125f : -1.0e30f;
      }
    }

    // online softmax update, per row r (state replicated across 16-lane group)
    float alpha[4], p[4][4];
#pragma unroll
    for (int r = 0; r < 4; ++r) {
      float tm = fmaxf(fmaxf(sc[0][r], sc[1][r]), fmaxf(sc[2][r], sc[3][r]));
      tm = fmaxf(tm, __shfl_xor(tm, 1, 64));
      tm = fmaxf(tm, __shfl_xor(tm, 2, 64));
      tm = fmaxf(tm, __shfl_xor(tm, 4, 64));
      tm = fmaxf(tm, __shfl_xor(tm, 8, 64));
      const float mn = fmaxf(m_i[r], tm);
      alpha[r] = __expf(m_i[r] - mn);
      m_i[r] = mn;
      float ps = 0.f;
#pragma unroll
      for (int nt = 0; nt < 4; ++nt) { p[nt][r] = __expf(sc[nt][r] - mn); ps += p[nt][r]; }
      ps += __shfl_xor(ps, 1, 64);
      ps += __shfl_xor(ps, 2, 64);
      ps += __shfl_xor(ps, 4, 64);
      ps += __shfl_xor(ps, 8, 64);
      l_i[r] = l_i[r] * alpha[r] + ps;
    }

    // P: C-layout regs -> LDS (bf16) -> A-layout frags
#pragma unroll
    for (int nt = 0; nt < 4; ++nt)
#pragma unroll
      for (int r = 0; r < 4; ++r)
        Ps[(wid * 16 + rowg * 4 + r) * 72 + nt * 16 + cl] = f2b(p[nt][r]);
    __syncthreads();                 // also aligns waves; intra-wave ds order

    // O = O*alpha + P @ V   (A = P rows, B = Vt[d][j])
#pragma unroll
    for (int nt = 0; nt < 4; ++nt)
#pragma unroll
      for (int r = 0; r < 4; ++r) O[nt][r] *= alpha[r];
    short8 aP[2];
#pragma unroll
    for (int ks = 0; ks < 2; ++ks)
      aP[ks] = *(const short8*)&Ps[(wid * 16 + cl) * 72 + ks * 32 + kq];
#pragma unroll
    for (int nt = 0; nt < 4; ++nt)
#pragma unroll
      for (int ks = 0; ks < 2; ++ks) {
        const short8 bV = *(const short8*)&Vt[(nt * 16 + cl) * 72 + ks * 32 + kq];
        O[nt] = __builtin_amdgcn_mfma_f32_16x16x32_bf16(aP[ks], bV, O[nt], 0, 0, 0);
      }
  }

  // epilogue: ctx[i][h*64+d] = O / l  (C-layout)
#pragma unroll
  for (int nt = 0; nt < 4; ++nt) {
    const int d = nt * 16 + cl;
#pragma unroll
    for (int r = 0; r < 4; ++r) {
      const int i = q0 + wid * 16 + rowg * 4 + r;
      ctx[(rowb + i) * 1024 + h * 64 + d] = f2b(O[nt][r] / l_i[r]);
    }
  }
}

// ---------------------------------------------------------------------------
// Residual + LayerNorm (unchanged from passing r5).
// ---------------------------------------------------------------------------
template<int AF32, int BF32, int OF32>
__global__ __launch_bounds__(256) void ln_k(
    const void* __restrict__ a, const void* __restrict__ b,
    const float* __restrict__ g, const float* __restrict__ be,
    void* __restrict__ o)
{
  __shared__ float rbuf[8];
  const int tid = threadIdx.x;
  const size_t base = (size_t)blockIdx.x * 1024;
  const int lane = tid & 63, wid = tid >> 6;

  float xv[4], s = 0.f, sq = 0.f;
#pragma unroll
  for (int t = 0; t < 4; ++t) {
    const int c = tid + t * 256;
    const float av = AF32 ? ((const float*)a)[base + c]
                          : b2f(((const unsigned short*)a)[base + c]);
    const float bv = BF32 ? ((const float*)b)[base + c]
                          : b2f(((const unsigned short*)b)[base + c]);
    const float x = av + bv;
    xv[t] = x; s += x; sq += x * x;
  }
  for (int o2 = 1; o2 < 64; o2 <<= 1) { s += __shfl_xor(s, o2, 64); sq += __shfl_xor(sq, o2, 64); }
  if (lane == 0) { rbuf[wid] = s; rbuf[wid + 4] = sq; }
  __syncthreads();
  s  = rbuf[0] + rbuf[1] + rbuf[2] + rbuf[3];
  sq = rbuf[4] + rbuf[5] + rbuf[6] + rbuf[7];
  const float mean = s * (1.0f / 1024.f);
  const float var = sq * (1.0f / 1024.f) - mean * mean;
  const float rstd = rsqrtf(var + 1e-5f);
#pragma unroll
  for (int t = 0; t < 4; ++t) {
    const int c = tid + t * 256;
    const float y = (xv[t] - mean) * rstd * g[c] + be[c];
    if (OF32) ((float*)o)[base + c] = y;
    else      ((unsigned short*)o)[base + c] = f2b(y);
  }
}

// ---------------------------------------------------------------------------
extern "C" void kernel_launch(void* const* d_in, const int* in_sizes, int n_in,
                              void* d_out, int out_size, void* d_ws, size_t ws_size,
                              hipStream_t stream)
{
  (void)in_sizes; (void)n_in; (void)out_size; (void)ws_size;
  const float* src   = (const float*)d_in[0];
  const float* w_in  = (const float*)d_in[1];
  const float* b_in  = (const float*)d_in[2];
  const float* w_out = (const float*)d_in[3];
  const float* b_out = (const float*)d_in[4];
  const float* w1    = (const float*)d_in[5];
  const float* b1    = (const float*)d_in[6];
  const float* w2    = (const float*)d_in[7];
  const float* b2    = (const float*)d_in[8];
  const float* g1    = (const float*)d_in[9];
  const float* be1   = (const float*)d_in[10];
  const float* g2    = (const float*)d_in[11];
  const float* be2   = (const float*)d_in[12];

  char* ws = (char*)d_ws;
  unsigned short* qkv   = (unsigned short*)(ws);                 // [0, 25165824)
  unsigned short* ctx   = (unsigned short*)(ws + 25165824);      // [25165824, 33554432)
  unsigned short* attnb = (unsigned short*)(ws + 33554432);      // [33554432, 41943040)
  unsigned short* x1b   = (unsigned short*)(ws);                 // reuse qkv [0, 8388608)
  unsigned short* ff1   = (unsigned short*)(ws + 8388608);       // [8388608, 41943040)
  float*          outf  = (float*)d_out;

  // 1) QKV projection -> bf16 qkv
  gemm_bt<0, 1, 0><<<dim3(48, 64), 256, 0, stream>>>(src, w_in, b_in, qkv, 4096, 3072, 1024);
  // 2) banded MFMA flash attention -> bf16 ctx
  attn_mfma<<<dim3(1024), 256, 0, stream>>>(qkv, ctx);
  // 3) output projection -> bf16 attnb
  gemm_bt<0, 0, 0><<<dim3(16, 64), 256, 0, stream>>>(ctx, w_out, b_out, attnb, 4096, 1024, 1024);
  // 4) LN1(src f32 + attnb bf16) -> bf16 x1b
  ln_k<1, 0, 0><<<dim3(4096), 256, 0, stream>>>(src, attnb, g1, be1, x1b);
  // 5) FF1 + ReLU -> bf16 ff1
  gemm_bt<1, 0, 0><<<dim3(64, 64), 256, 0, stream>>>(x1b, w1, b1, ff1, 4096, 4096, 1024);
  // 6) FF2 -> f32 into d_out
  gemm_bt<0, 0, 1><<<dim3(16, 64), 256, 0, stream>>>(ff1, w2, b2, outf, 4096, 1024, 4096);
  // 7) LN2(x1b bf16 + d_out f32) -> f32 d_out (in-place, per-row safe)
  ln_k<0, 1, 1><<<dim3(4096), 256, 0, stream>>>(x1b, outf, g2, be2, outf);
}

// Round 7
// 388.743 us; speedup vs baseline: 3.5973x; 1.1742x over previous
//
#include <hip/hip_runtime.h>
#include <cstdint>
#include <cstddef>

// ---------------------------------------------------------------------------
// RestrictedTransformerEncoderLayer on MI355X (gfx950)  — ROUND 7
// B=2, L=2048, E=1024, H=16, D=64, FF=4096, WIN=128.
// External I/O f32; intermediates bf16; output f32.
// R7: GEMMs -> m97-style 128x128 tile + global_load_lds(16B) with swizzled
// LDS (rot chunk (r>>1)&3: conflict-free, no padding). Weights converted
// f32->bf16 just-in-time into one reusable 8.4MB slot.
// Workspace (peak 50.33 MB):
//   qkv  bf16 [0,        25165824)   dead after attn
//   ctx  bf16 [25165824, 33554432)   dead after out-proj
//   attnb bf16[33554432, 41943040)   dead after LN1
//   x1b  bf16 [0,         8388608)   (reuses qkv)  live till LN2
//   ff1  bf16 [8388608,  41943040)   (reuses qkv tail + ctx + attnb)
//   wslot bf16[41943040, 50331648)   current converted weight (serial reuse)
// ---------------------------------------------------------------------------

typedef __attribute__((ext_vector_type(8))) short short8;   // 8 x bf16 MFMA frag
typedef __attribute__((ext_vector_type(4))) float f32x4;    // MFMA accumulator

__device__ __forceinline__ float b2f(unsigned short u) {
  union { unsigned int i; float f; } x; x.i = ((unsigned int)u) << 16; return x.f;
}
__device__ __forceinline__ unsigned short f2b(float f) {
  union { float f; unsigned int i; } x; x.f = f;
  unsigned int i = x.i;
  unsigned int r = (i + 0x7FFFu + ((i >> 16) & 1u)) >> 16;  // RNE
  return (unsigned short)r;
}
__device__ __forceinline__ uint4 pack8(float4 f0, float4 f1) {
  uint4 r;
  r.x = (unsigned)f2b(f0.x) | ((unsigned)f2b(f0.y) << 16);
  r.y = (unsigned)f2b(f0.z) | ((unsigned)f2b(f0.w) << 16);
  r.z = (unsigned)f2b(f1.x) | ((unsigned)f2b(f1.y) << 16);
  r.w = (unsigned)f2b(f1.z) | ((unsigned)f2b(f1.w) << 16);
  return r;
}

// async global->LDS, 16B per lane; lds base must be wave-uniform (m104/m108)
__device__ __forceinline__ void gl_lds16(const unsigned short* g, unsigned short* l) {
  __builtin_amdgcn_global_load_lds(
      (const __attribute__((address_space(1))) unsigned int*)g,
      (__attribute__((address_space(3))) unsigned int*)l, 16, 0, 0);
}

// ---------------------------------------------------------------------------
// f32 -> bf16 convert (grid: n/2048 blocks x 256 thr, 8 elems/thread)
// ---------------------------------------------------------------------------
__global__ __launch_bounds__(256) void conv_k(
    const float* __restrict__ in, unsigned short* __restrict__ out, int n)
{
  const int i = (blockIdx.x * 256 + threadIdx.x) * 8;
  if (i < n) {
    const float4 f0 = *(const float4*)(in + i);
    const float4 f1 = *(const float4*)(in + i + 4);
    *(uint4*)(out + i) = pack8(f0, f1);
  }
}

// ---------------------------------------------------------------------------
// GEMM 128x128 tile, BK=32: out[M,N] = A[M,K] @ W[N,K]^T + bias.
// W: bf16 (pre-converted), staged via global_load_lds. A: bf16 staged async
// (AF32=0) or f32 staged via VGPR+pack8 (AF32=1, QKV only).
// LDS swizzle: slot (r,s) holds global 16B-chunk c=(s+(r>>1))&3 of row r;
// reader for k-group kg uses s=(kg-(r>>1))&3. 2-way max bank alias (free).
// 4 waves in 2x2; wave = 64x64 = 4x4 MFMAs of 16x16x32. 16 KB LDS.
// ---------------------------------------------------------------------------
template<int RELU, int AF32, int OUT32>
__global__ __launch_bounds__(256) void gemm128(
    const void* __restrict__ Av, const unsigned short* __restrict__ Wb,
    const float* __restrict__ bias, void* __restrict__ out,
    int M, int N, int K)
{
  __shared__ unsigned short As[128 * 32];   // 8 KB
  __shared__ unsigned short Bs[128 * 32];   // 8 KB

  const int tid = threadIdx.x;
  const int lane = tid & 63, wid = tid >> 6;
  const int m0 = blockIdx.y * 128, n0 = blockIdx.x * 128;

  // staging slots: thread covers slot tid (rows 0..63) and tid+256 (rows 64..127)
  const int r0 = tid >> 2, s0 = tid & 3;
  const int c0 = (s0 + (r0 >> 1)) & 3;      // note: slot+256 -> r+64, same c
  const int r1 = r0 + 64;

  const unsigned short* gW0 = Wb + (size_t)(n0 + r0) * K + c0 * 8;
  const unsigned short* gW1 = Wb + (size_t)(n0 + r1) * K + c0 * 8;
  const unsigned short* gA0 = (const unsigned short*)Av + (size_t)(m0 + r0) * K + c0 * 8;
  const unsigned short* gA1 = (const unsigned short*)Av + (size_t)(m0 + r1) * K + c0 * 8;
  const float* gAf0 = (const float*)Av + (size_t)(m0 + r0) * K + c0 * 8;
  const float* gAf1 = (const float*)Av + (size_t)(m0 + r1) * K + c0 * 8;

  // MFMA fragment indexing
  const int cl = lane & 15;          // A/B row within 16-tile; C/D col
  const int kg = lane >> 4;          // k-group (k = kg*8 + j); C/D row group
  const int msub = (wid >> 1) * 64, nsub = (wid & 1) * 64;
  int aoffs[4], boffs[4];
#pragma unroll
  for (int t = 0; t < 4; ++t) {
    const int ar = msub + t * 16 + cl;
    aoffs[t] = ar * 32 + ((kg - (ar >> 1)) & 3) * 8;
    const int br = nsub + t * 16 + cl;
    boffs[t] = br * 32 + ((kg - (br >> 1)) & 3) * 8;
  }

  f32x4 acc[4][4];
#pragma unroll
  for (int i = 0; i < 4; ++i)
#pragma unroll
    for (int j = 0; j < 4; ++j) acc[i][j] = (f32x4){0.f, 0.f, 0.f, 0.f};

  const int steps = K >> 5;
  for (int s = 0; s < steps; ++s) {
    if (AF32) {
      const uint4 av0 = pack8(*(const float4*)gAf0, *(const float4*)(gAf0 + 4));
      const uint4 av1 = pack8(*(const float4*)gAf1, *(const float4*)(gAf1 + 4));
      *(uint4*)&As[tid * 8] = av0;              // slot tid
      *(uint4*)&As[(tid + 256) * 8] = av1;      // slot tid+256
      gAf0 += 32; gAf1 += 32;
    } else {
      gl_lds16(gA0, &As[wid * 512]);            // slots [wid*64, +64)
      gl_lds16(gA1, &As[2048 + wid * 512]);     // slots [256+wid*64, +64)
      gA0 += 32; gA1 += 32;
    }
    gl_lds16(gW0, &Bs[wid * 512]);
    gl_lds16(gW1, &Bs[2048 + wid * 512]);
    gW0 += 32; gW1 += 32;
    __syncthreads();                            // drains vmcnt + lgkm

    short8 af[4], bf[4];
#pragma unroll
    for (int t = 0; t < 4; ++t) af[t] = *(const short8*)&As[aoffs[t]];
#pragma unroll
    for (int t = 0; t < 4; ++t) bf[t] = *(const short8*)&Bs[boffs[t]];
#pragma unroll
    for (int mt = 0; mt < 4; ++mt)
#pragma unroll
      for (int nt = 0; nt < 4; ++nt)
        acc[mt][nt] = __builtin_amdgcn_mfma_f32_16x16x32_bf16(af[mt], bf[nt], acc[mt][nt], 0, 0, 0);
    __syncthreads();
  }

  // epilogue: C/D mapping col = cl, row = kg*4 + r  [m89-verified]
#pragma unroll
  for (int nt = 0; nt < 4; ++nt) {
    const int col = n0 + nsub + nt * 16 + cl;
    const float bvs = bias[col];
#pragma unroll
    for (int mt = 0; mt < 4; ++mt) {
#pragma unroll
      for (int r = 0; r < 4; ++r) {
        const int grow = m0 + msub + mt * 16 + kg * 4 + r;
        float v = acc[mt][nt][r] + bvs;
        if (RELU) v = fmaxf(v, 0.f);
        if (OUT32) ((float*)out)[(size_t)grow * N + col] = v;
        else       ((unsigned short*)out)[(size_t)grow * N + col] = f2b(v);
      }
    }
  }
}

// ---------------------------------------------------------------------------
// MFMA flash attention (unchanged from passing r6).
// ---------------------------------------------------------------------------
__global__ __launch_bounds__(256) void attn_mfma(
    const unsigned short* __restrict__ qkv, unsigned short* __restrict__ ctx)
{
  __shared__ unsigned short Ks[64 * 72];   // [j][d]
  __shared__ unsigned short Vt[64 * 72];   // [d][j]
  __shared__ unsigned short Ps[64 * 72];   // [q][j]

  const int tid = threadIdx.x;
  const int bid = blockIdx.x;
  const int qt = bid & 31, h = (bid >> 5) & 15, b = bid >> 9;
  const int q0 = qt * 64;
  const int wstart = max(0, q0 - 128);
  const int wend = min(2048, q0 + 64 + 128);
  const int ntile = (wend - wstart + 63) >> 6;
  const size_t rowb = (size_t)b * 2048;

  const int lane = tid & 63, wid = tid >> 6;
  const int cl = lane & 15;
  const int kq = (lane >> 4) * 8;
  const int rowg = lane >> 4;

  short8 aQ[2];
#pragma unroll
  for (int ks = 0; ks < 2; ++ks)
    aQ[ks] = *(const short8*)(qkv + (rowb + q0 + wid * 16 + cl) * 3072 + h * 64 + ks * 32 + kq);

  float m_i[4], l_i[4];
  f32x4 O[4];
#pragma unroll
  for (int r = 0; r < 4; ++r) { m_i[r] = -1.0e30f; l_i[r] = 0.f; }
#pragma unroll
  for (int nt = 0; nt < 4; ++nt) O[nt] = (f32x4){0.f, 0.f, 0.f, 0.f};

  for (int t = 0; t < ntile; ++t) {
    const int jbase = wstart + t * 64;
    __syncthreads();
    for (int idx = tid; idx < 512; idx += 256) {
      const int r = idx >> 3, c = idx & 7;
      const int jg = jbase + r;
      uint4 kv = {0u, 0u, 0u, 0u}, vv = {0u, 0u, 0u, 0u};
      if (jg < wend) {
        const size_t base = (rowb + jg) * 3072 + h * 64 + c * 8;
        kv = *(const uint4*)(qkv + base + 1024);
        vv = *(const uint4*)(qkv + base + 2048);
      }
      *(uint4*)&Ks[r * 72 + c * 8] = kv;
      const unsigned short* vs = (const unsigned short*)&vv;
#pragma unroll
      for (int ii = 0; ii < 8; ++ii) Vt[(c * 8 + ii) * 72 + r] = vs[ii];
    }
    __syncthreads();

    f32x4 S[4];
#pragma unroll
    for (int nt = 0; nt < 4; ++nt) S[nt] = (f32x4){0.f, 0.f, 0.f, 0.f};
#pragma unroll
    for (int nt = 0; nt < 4; ++nt)
#pragma unroll
      for (int ks = 0; ks < 2; ++ks) {
        const short8 bK = *(const short8*)&Ks[(nt * 16 + cl) * 72 + ks * 32 + kq];
        S[nt] = __builtin_amdgcn_mfma_f32_16x16x32_bf16(aQ[ks], bK, S[nt], 0, 0, 0);
      }

    float sc[4][4];
#pragma unroll
    for (int nt = 0; nt < 4; ++nt) {
      const int jg = jbase + nt * 16 + cl;
#pragma unroll
      for (int r = 0; r < 4; ++r) {
        const int i = q0 + wid * 16 + rowg * 4 + r;
        const bool v = (jg < wend) && (jg >= i - 128) && (jg <= i + 128);
        sc[nt][r] = v ? S[nt][r] * 0.125f : -1.0e30f;
      }
    }

    float alpha[4], p[4][4];
#pragma unroll
    for (int r = 0; r < 4; ++r) {
      float tm = fmaxf(fmaxf(sc[0][r], sc[1][r]), fmaxf(sc[2][r], sc[3][r]));
      tm = fmaxf(tm, __shfl_xor(tm, 1, 64));
      tm = fmaxf(tm, __shfl_xor(tm, 2, 64));
      tm = fmaxf(tm, __shfl_xor(tm, 4, 64));
      tm = fmaxf(tm, __shfl_xor(tm, 8, 64));
      const float mn = fmaxf(m_i[r], tm);
      alpha[r] = __expf(m_i[r] - mn);
      m_i[r] = mn;
      float ps = 0.f;
#pragma unroll
      for (int nt = 0; nt < 4; ++nt) { p[nt][r] = __expf(sc[nt][r] - mn); ps += p[nt][r]; }
      ps += __shfl_xor(ps, 1, 64);
      ps += __shfl_xor(ps, 2, 64);
      ps += __shfl_xor(ps, 4, 64);
      ps += __shfl_xor(ps, 8, 64);
      l_i[r] = l_i[r] * alpha[r] + ps;
    }

#pragma unroll
    for (int nt = 0; nt < 4; ++nt)
#pragma unroll
      for (int r = 0; r < 4; ++r)
        Ps[(wid * 16 + rowg * 4 + r) * 72 + nt * 16 + cl] = f2b(p[nt][r]);
    __syncthreads();

#pragma unroll
    for (int nt = 0; nt < 4; ++nt)
#pragma unroll
      for (int r = 0; r < 4; ++r) O[nt][r] *= alpha[r];
    short8 aP[2];
#pragma unroll
    for (int ks = 0; ks < 2; ++ks)
      aP[ks] = *(const short8*)&Ps[(wid * 16 + cl) * 72 + ks * 32 + kq];
#pragma unroll
    for (int nt = 0; nt < 4; ++nt)
#pragma unroll
      for (int ks = 0; ks < 2; ++ks) {
        const short8 bV = *(const short8*)&Vt[(nt * 16 + cl) * 72 + ks * 32 + kq];
        O[nt] = __builtin_amdgcn_mfma_f32_16x16x32_bf16(aP[ks], bV, O[nt], 0, 0, 0);
      }
  }

#pragma unroll
  for (int nt = 0; nt < 4; ++nt) {
    const int d = nt * 16 + cl;
#pragma unroll
    for (int r = 0; r < 4; ++r) {
      const int i = q0 + wid * 16 + rowg * 4 + r;
      ctx[(rowb + i) * 1024 + h * 64 + d] = f2b(O[nt][r] / l_i[r]);
    }
  }
}

// ---------------------------------------------------------------------------
// Residual + LayerNorm (unchanged from passing r5/r6).
// ---------------------------------------------------------------------------
template<int AF32, int BF32, int OF32>
__global__ __launch_bounds__(256) void ln_k(
    const void* __restrict__ a, const void* __restrict__ b,
    const float* __restrict__ g, const float* __restrict__ be,
    void* __restrict__ o)
{
  __shared__ float rbuf[8];
  const int tid = threadIdx.x;
  const size_t base = (size_t)blockIdx.x * 1024;
  const int lane = tid & 63, wid = tid >> 6;

  float xv[4], s = 0.f, sq = 0.f;
#pragma unroll
  for (int t = 0; t < 4; ++t) {
    const int c = tid + t * 256;
    const float av = AF32 ? ((const float*)a)[base + c]
                          : b2f(((const unsigned short*)a)[base + c]);
    const float bv = BF32 ? ((const float*)b)[base + c]
                          : b2f(((const unsigned short*)b)[base + c]);
    const float x = av + bv;
    xv[t] = x; s += x; sq += x * x;
  }
  for (int o2 = 1; o2 < 64; o2 <<= 1) { s += __shfl_xor(s, o2, 64); sq += __shfl_xor(sq, o2, 64); }
  if (lane == 0) { rbuf[wid] = s; rbuf[wid + 4] = sq; }
  __syncthreads();
  s  = rbuf[0] + rbuf[1] + rbuf[2] + rbuf[3];
  sq = rbuf[4] + rbuf[5] + rbuf[6] + rbuf[7];
  const float mean = s * (1.0f / 1024.f);
  const float var = sq * (1.0f / 1024.f) - mean * mean;
  const float rstd = rsqrtf(var + 1e-5f);
#pragma unroll
  for (int t = 0; t < 4; ++t) {
    const int c = tid + t * 256;
    const float y = (xv[t] - mean) * rstd * g[c] + be[c];
    if (OF32) ((float*)o)[base + c] = y;
    else      ((unsigned short*)o)[base + c] = f2b(y);
  }
}

// ---------------------------------------------------------------------------
extern "C" void kernel_launch(void* const* d_in, const int* in_sizes, int n_in,
                              void* d_out, int out_size, void* d_ws, size_t ws_size,
                              hipStream_t stream)
{
  (void)in_sizes; (void)n_in; (void)out_size; (void)ws_size;
  const float* src   = (const float*)d_in[0];
  const float* w_in  = (const float*)d_in[1];
  const float* b_in  = (const float*)d_in[2];
  const float* w_out = (const float*)d_in[3];
  const float* b_out = (const float*)d_in[4];
  const float* w1    = (const float*)d_in[5];
  const float* b1    = (const float*)d_in[6];
  const float* w2    = (const float*)d_in[7];
  const float* b2    = (const float*)d_in[8];
  const float* g1    = (const float*)d_in[9];
  const float* be1   = (const float*)d_in[10];
  const float* g2    = (const float*)d_in[11];
  const float* be2   = (const float*)d_in[12];

  char* ws = (char*)d_ws;
  unsigned short* qkv   = (unsigned short*)(ws);                 // [0, 25165824)
  unsigned short* ctx   = (unsigned short*)(ws + 25165824);      // [25165824, 33554432)
  unsigned short* attnb = (unsigned short*)(ws + 33554432);      // [33554432, 41943040)
  unsigned short* x1b   = (unsigned short*)(ws);                 // reuse qkv [0, 8388608)
  unsigned short* ff1   = (unsigned short*)(ws + 8388608);       // [8388608, 41943040)
  unsigned short* wslot = (unsigned short*)(ws + 41943040);      // [41943040, 50331648)
  float*          outf  = (float*)d_out;

  // 1) convert in_proj_w -> bf16; QKV projection -> bf16 qkv
  conv_k<<<dim3(1536), 256, 0, stream>>>(w_in, wslot, 3145728);
  gemm128<0, 1, 0><<<dim3(24, 32), 256, 0, stream>>>(src, wslot, b_in, qkv, 4096, 3072, 1024);
  // 2) banded MFMA flash attention -> bf16 ctx
  attn_mfma<<<dim3(1024), 256, 0, stream>>>(qkv, ctx);
  // 3) convert out_w; output projection -> bf16 attnb
  conv_k<<<dim3(512), 256, 0, stream>>>(w_out, wslot, 1048576);
  gemm128<0, 0, 0><<<dim3(8, 32), 256, 0, stream>>>(ctx, wslot, b_out, attnb, 4096, 1024, 1024);
  // 4) LN1(src f32 + attnb bf16) -> bf16 x1b
  ln_k<1, 0, 0><<<dim3(4096), 256, 0, stream>>>(src, attnb, g1, be1, x1b);
  // 5) convert lin1_w; FF1 + ReLU -> bf16 ff1
  conv_k<<<dim3(2048), 256, 0, stream>>>(w1, wslot, 4194304);
  gemm128<1, 0, 0><<<dim3(32, 32), 256, 0, stream>>>(x1b, wslot, b1, ff1, 4096, 4096, 1024);
  // 6) convert lin2_w; FF2 -> f32 into d_out
  conv_k<<<dim3(2048), 256, 0, stream>>>(w2, wslot, 4194304);
  gemm128<0, 0, 1><<<dim3(8, 32), 256, 0, stream>>>(ff1, wslot, b2, outf, 4096, 1024, 4096);
  // 7) LN2(x1b bf16 + d_out f32) -> f32 d_out (in-place, per-row safe)
  ln_k<0, 1, 1><<<dim3(4096), 256, 0, stream>>>(x1b, outf, g2, be2, outf);
}

// Round 8
// 369.332 us; speedup vs baseline: 3.7863x; 1.0526x over previous
//
#include <hip/hip_runtime.h>
#include <cstdint>
#include <cstddef>

// ---------------------------------------------------------------------------
// RestrictedTransformerEncoderLayer on MI355X (gfx950)  — ROUND 8
// B=2, L=2048, E=1024, H=16, D=64, FF=4096, WIN=128.
// External I/O f32; intermediates bf16; output f32.
// R8: N=1024 GEMMs (out-proj, FF2) were 1 block/CU (grid 256) -> barrier
// drains fully exposed (Occ 10.8%). New gemm64: BM=64 tile -> 512 blocks,
// 2 blocks/CU, cross-block MFMA/drain overlap (m114).
// Workspace (peak 50.33 MB):
//   qkv  bf16 [0,        25165824)   dead after attn
//   ctx  bf16 [25165824, 33554432)   dead after out-proj
//   attnb bf16[33554432, 41943040)   dead after LN1
//   x1b  bf16 [0,         8388608)   (reuses qkv)  live till LN2
//   ff1  bf16 [8388608,  41943040)
//   wslot bf16[41943040, 50331648)   current converted weight (serial reuse)
// ---------------------------------------------------------------------------

typedef __attribute__((ext_vector_type(8))) short short8;   // 8 x bf16 MFMA frag
typedef __attribute__((ext_vector_type(4))) float f32x4;    // MFMA accumulator

__device__ __forceinline__ float b2f(unsigned short u) {
  union { unsigned int i; float f; } x; x.i = ((unsigned int)u) << 16; return x.f;
}
__device__ __forceinline__ unsigned short f2b(float f) {
  union { float f; unsigned int i; } x; x.f = f;
  unsigned int i = x.i;
  unsigned int r = (i + 0x7FFFu + ((i >> 16) & 1u)) >> 16;  // RNE
  return (unsigned short)r;
}
__device__ __forceinline__ uint4 pack8(float4 f0, float4 f1) {
  uint4 r;
  r.x = (unsigned)f2b(f0.x) | ((unsigned)f2b(f0.y) << 16);
  r.y = (unsigned)f2b(f0.z) | ((unsigned)f2b(f0.w) << 16);
  r.z = (unsigned)f2b(f1.x) | ((unsigned)f2b(f1.y) << 16);
  r.w = (unsigned)f2b(f1.z) | ((unsigned)f2b(f1.w) << 16);
  return r;
}

// async global->LDS, 16B per lane; lds base must be wave-uniform (m104/m108)
__device__ __forceinline__ void gl_lds16(const unsigned short* g, unsigned short* l) {
  __builtin_amdgcn_global_load_lds(
      (const __attribute__((address_space(1))) unsigned int*)g,
      (__attribute__((address_space(3))) unsigned int*)l, 16, 0, 0);
}

// ---------------------------------------------------------------------------
// f32 -> bf16 convert
// ---------------------------------------------------------------------------
__global__ __launch_bounds__(256) void conv_k(
    const float* __restrict__ in, unsigned short* __restrict__ out, int n)
{
  const int i = (blockIdx.x * 256 + threadIdx.x) * 8;
  if (i < n) {
    const float4 f0 = *(const float4*)(in + i);
    const float4 f1 = *(const float4*)(in + i + 4);
    *(uint4*)(out + i) = pack8(f0, f1);
  }
}

// ---------------------------------------------------------------------------
// GEMM 128x128 tile, BK=32 (unchanged from passing r7).
// LDS swizzle: slot (r,s) holds chunk c=(s+(r>>1))&3; reader s=(kg-(r>>1))&3.
// ---------------------------------------------------------------------------
template<int RELU, int AF32, int OUT32>
__global__ __launch_bounds__(256) void gemm128(
    const void* __restrict__ Av, const unsigned short* __restrict__ Wb,
    const float* __restrict__ bias, void* __restrict__ out,
    int M, int N, int K)
{
  __shared__ unsigned short As[128 * 32];
  __shared__ unsigned short Bs[128 * 32];

  const int tid = threadIdx.x;
  const int lane = tid & 63, wid = tid >> 6;
  const int m0 = blockIdx.y * 128, n0 = blockIdx.x * 128;

  const int r0 = tid >> 2, s0 = tid & 3;
  const int c0 = (s0 + (r0 >> 1)) & 3;
  const int r1 = r0 + 64;

  const unsigned short* gW0 = Wb + (size_t)(n0 + r0) * K + c0 * 8;
  const unsigned short* gW1 = Wb + (size_t)(n0 + r1) * K + c0 * 8;
  const unsigned short* gA0 = (const unsigned short*)Av + (size_t)(m0 + r0) * K + c0 * 8;
  const unsigned short* gA1 = (const unsigned short*)Av + (size_t)(m0 + r1) * K + c0 * 8;
  const float* gAf0 = (const float*)Av + (size_t)(m0 + r0) * K + c0 * 8;
  const float* gAf1 = (const float*)Av + (size_t)(m0 + r1) * K + c0 * 8;

  const int cl = lane & 15;
  const int kg = lane >> 4;
  const int msub = (wid >> 1) * 64, nsub = (wid & 1) * 64;
  int aoffs[4], boffs[4];
#pragma unroll
  for (int t = 0; t < 4; ++t) {
    const int ar = msub + t * 16 + cl;
    aoffs[t] = ar * 32 + ((kg - (ar >> 1)) & 3) * 8;
    const int br = nsub + t * 16 + cl;
    boffs[t] = br * 32 + ((kg - (br >> 1)) & 3) * 8;
  }

  f32x4 acc[4][4];
#pragma unroll
  for (int i = 0; i < 4; ++i)
#pragma unroll
    for (int j = 0; j < 4; ++j) acc[i][j] = (f32x4){0.f, 0.f, 0.f, 0.f};

  const int steps = K >> 5;
  for (int s = 0; s < steps; ++s) {
    if (AF32) {
      const uint4 av0 = pack8(*(const float4*)gAf0, *(const float4*)(gAf0 + 4));
      const uint4 av1 = pack8(*(const float4*)gAf1, *(const float4*)(gAf1 + 4));
      *(uint4*)&As[tid * 8] = av0;
      *(uint4*)&As[(tid + 256) * 8] = av1;
      gAf0 += 32; gAf1 += 32;
    } else {
      gl_lds16(gA0, &As[wid * 512]);
      gl_lds16(gA1, &As[2048 + wid * 512]);
      gA0 += 32; gA1 += 32;
    }
    gl_lds16(gW0, &Bs[wid * 512]);
    gl_lds16(gW1, &Bs[2048 + wid * 512]);
    gW0 += 32; gW1 += 32;
    __syncthreads();

    short8 af[4], bf[4];
#pragma unroll
    for (int t = 0; t < 4; ++t) af[t] = *(const short8*)&As[aoffs[t]];
#pragma unroll
    for (int t = 0; t < 4; ++t) bf[t] = *(const short8*)&Bs[boffs[t]];
#pragma unroll
    for (int mt = 0; mt < 4; ++mt)
#pragma unroll
      for (int nt = 0; nt < 4; ++nt)
        acc[mt][nt] = __builtin_amdgcn_mfma_f32_16x16x32_bf16(af[mt], bf[nt], acc[mt][nt], 0, 0, 0);
    __syncthreads();
  }

#pragma unroll
  for (int nt = 0; nt < 4; ++nt) {
    const int col = n0 + nsub + nt * 16 + cl;
    const float bvs = bias[col];
#pragma unroll
    for (int mt = 0; mt < 4; ++mt) {
#pragma unroll
      for (int r = 0; r < 4; ++r) {
        const int grow = m0 + msub + mt * 16 + kg * 4 + r;
        float v = acc[mt][nt][r] + bvs;
        if (RELU) v = fmaxf(v, 0.f);
        if (OUT32) ((float*)out)[(size_t)grow * N + col] = v;
        else       ((unsigned short*)out)[(size_t)grow * N + col] = f2b(v);
      }
    }
  }
}

// ---------------------------------------------------------------------------
// GEMM 64x128 tile, BK=32 — for N=1024 shapes (grid 512 = 2 blocks/CU).
// 4 waves, wave w owns cols [w*32, +32) of the 128-col tile, all 64 rows.
// A: bf16 only. Same LDS chunk-rotation swizzle. 12 KB LDS, acc = 32 VGPRs.
// ---------------------------------------------------------------------------
template<int OUT32>
__global__ __launch_bounds__(256) void gemm64(
    const unsigned short* __restrict__ A, const unsigned short* __restrict__ Wb,
    const float* __restrict__ bias, void* __restrict__ out,
    int M, int N, int K)
{
  __shared__ unsigned short As[64 * 32];    // 4 KB
  __shared__ unsigned short Bs[128 * 32];   // 8 KB

  const int tid = threadIdx.x;
  const int lane = tid & 63, wid = tid >> 6;
  const int m0 = blockIdx.y * 64, n0 = blockIdx.x * 128;

  const int r0 = tid >> 2, s0 = tid & 3;
  const int c0 = (s0 + (r0 >> 1)) & 3;
  const int r1 = r0 + 64;                    // B rows 64..127

  const unsigned short* gA0 = A + (size_t)(m0 + r0) * K + c0 * 8;
  const unsigned short* gW0 = Wb + (size_t)(n0 + r0) * K + c0 * 8;
  const unsigned short* gW1 = Wb + (size_t)(n0 + r1) * K + c0 * 8;

  const int cl = lane & 15;
  const int kg = lane >> 4;
  int aoffs[4], boffs[2];
#pragma unroll
  for (int t = 0; t < 4; ++t) {
    const int ar = t * 16 + cl;
    aoffs[t] = ar * 32 + ((kg - (ar >> 1)) & 3) * 8;
  }
#pragma unroll
  for (int t = 0; t < 2; ++t) {
    const int br = wid * 32 + t * 16 + cl;
    boffs[t] = br * 32 + ((kg - (br >> 1)) & 3) * 8;
  }

  f32x4 acc[4][2];
#pragma unroll
  for (int i = 0; i < 4; ++i)
#pragma unroll
    for (int j = 0; j < 2; ++j) acc[i][j] = (f32x4){0.f, 0.f, 0.f, 0.f};

  const int steps = K >> 5;
  for (int s = 0; s < steps; ++s) {
    gl_lds16(gA0, &As[wid * 512]);            // A slots [wid*64, +64)
    gl_lds16(gW0, &Bs[wid * 512]);
    gl_lds16(gW1, &Bs[2048 + wid * 512]);
    gA0 += 32; gW0 += 32; gW1 += 32;
    __syncthreads();

    short8 af[4], bf[2];
#pragma unroll
    for (int t = 0; t < 4; ++t) af[t] = *(const short8*)&As[aoffs[t]];
#pragma unroll
    for (int t = 0; t < 2; ++t) bf[t] = *(const short8*)&Bs[boffs[t]];
#pragma unroll
    for (int mt = 0; mt < 4; ++mt)
#pragma unroll
      for (int nt = 0; nt < 2; ++nt)
        acc[mt][nt] = __builtin_amdgcn_mfma_f32_16x16x32_bf16(af[mt], bf[nt], acc[mt][nt], 0, 0, 0);
    __syncthreads();
  }

#pragma unroll
  for (int nt = 0; nt < 2; ++nt) {
    const int col = n0 + wid * 32 + nt * 16 + cl;
    const float bvs = bias[col];
#pragma unroll
    for (int mt = 0; mt < 4; ++mt) {
#pragma unroll
      for (int r = 0; r < 4; ++r) {
        const int grow = m0 + mt * 16 + kg * 4 + r;
        const float v = acc[mt][nt][r] + bvs;
        if (OUT32) ((float*)out)[(size_t)grow * N + col] = v;
        else       ((unsigned short*)out)[(size_t)grow * N + col] = f2b(v);
      }
    }
  }
}

// ---------------------------------------------------------------------------
// MFMA flash attention (unchanged from passing r6/r7).
// ---------------------------------------------------------------------------
__global__ __launch_bounds__(256) void attn_mfma(
    const unsigned short* __restrict__ qkv, unsigned short* __restrict__ ctx)
{
  __shared__ unsigned short Ks[64 * 72];
  __shared__ unsigned short Vt[64 * 72];
  __shared__ unsigned short Ps[64 * 72];

  const int tid = threadIdx.x;
  const int bid = blockIdx.x;
  const int qt = bid & 31, h = (bid >> 5) & 15, b = bid >> 9;
  const int q0 = qt * 64;
  const int wstart = max(0, q0 - 128);
  const int wend = min(2048, q0 + 64 + 128);
  const int ntile = (wend - wstart + 63) >> 6;
  const size_t rowb = (size_t)b * 2048;

  const int lane = tid & 63, wid = tid >> 6;
  const int cl = lane & 15;
  const int kq = (lane >> 4) * 8;
  const int rowg = lane >> 4;

  short8 aQ[2];
#pragma unroll
  for (int ks = 0; ks < 2; ++ks)
    aQ[ks] = *(const short8*)(qkv + (rowb + q0 + wid * 16 + cl) * 3072 + h * 64 + ks * 32 + kq);

  float m_i[4], l_i[4];
  f32x4 O[4];
#pragma unroll
  for (int r = 0; r < 4; ++r) { m_i[r] = -1.0e30f; l_i[r] = 0.f; }
#pragma unroll
  for (int nt = 0; nt < 4; ++nt) O[nt] = (f32x4){0.f, 0.f, 0.f, 0.f};

  for (int t = 0; t < ntile; ++t) {
    const int jbase = wstart + t * 64;
    __syncthreads();
    for (int idx = tid; idx < 512; idx += 256) {
      const int r = idx >> 3, c = idx & 7;
      const int jg = jbase + r;
      uint4 kv = {0u, 0u, 0u, 0u}, vv = {0u, 0u, 0u, 0u};
      if (jg < wend) {
        const size_t base = (rowb + jg) * 3072 + h * 64 + c * 8;
        kv = *(const uint4*)(qkv + base + 1024);
        vv = *(const uint4*)(qkv + base + 2048);
      }
      *(uint4*)&Ks[r * 72 + c * 8] = kv;
      const unsigned short* vs = (const unsigned short*)&vv;
#pragma unroll
      for (int ii = 0; ii < 8; ++ii) Vt[(c * 8 + ii) * 72 + r] = vs[ii];
    }
    __syncthreads();

    f32x4 S[4];
#pragma unroll
    for (int nt = 0; nt < 4; ++nt) S[nt] = (f32x4){0.f, 0.f, 0.f, 0.f};
#pragma unroll
    for (int nt = 0; nt < 4; ++nt)
#pragma unroll
      for (int ks = 0; ks < 2; ++ks) {
        const short8 bK = *(const short8*)&Ks[(nt * 16 + cl) * 72 + ks * 32 + kq];
        S[nt] = __builtin_amdgcn_mfma_f32_16x16x32_bf16(aQ[ks], bK, S[nt], 0, 0, 0);
      }

    float sc[4][4];
#pragma unroll
    for (int nt = 0; nt < 4; ++nt) {
      const int jg = jbase + nt * 16 + cl;
#pragma unroll
      for (int r = 0; r < 4; ++r) {
        const int i = q0 + wid * 16 + rowg * 4 + r;
        const bool v = (jg < wend) && (jg >= i - 128) && (jg <= i + 128);
        sc[nt][r] = v ? S[nt][r] * 0.125f : -1.0e30f;
      }
    }

    float alpha[4], p[4][4];
#pragma unroll
    for (int r = 0; r < 4; ++r) {
      float tm = fmaxf(fmaxf(sc[0][r], sc[1][r]), fmaxf(sc[2][r], sc[3][r]));
      tm = fmaxf(tm, __shfl_xor(tm, 1, 64));
      tm = fmaxf(tm, __shfl_xor(tm, 2, 64));
      tm = fmaxf(tm, __shfl_xor(tm, 4, 64));
      tm = fmaxf(tm, __shfl_xor(tm, 8, 64));
      const float mn = fmaxf(m_i[r], tm);
      alpha[r] = __expf(m_i[r] - mn);
      m_i[r] = mn;
      float ps = 0.f;
#pragma unroll
      for (int nt = 0; nt < 4; ++nt) { p[nt][r] = __expf(sc[nt][r] - mn); ps += p[nt][r]; }
      ps += __shfl_xor(ps, 1, 64);
      ps += __shfl_xor(ps, 2, 64);
      ps += __shfl_xor(ps, 4, 64);
      ps += __shfl_xor(ps, 8, 64);
      l_i[r] = l_i[r] * alpha[r] + ps;
    }

#pragma unroll
    for (int nt = 0; nt < 4; ++nt)
#pragma unroll
      for (int r = 0; r < 4; ++r)
        Ps[(wid * 16 + rowg * 4 + r) * 72 + nt * 16 + cl] = f2b(p[nt][r]);
    __syncthreads();

#pragma unroll
    for (int nt = 0; nt < 4; ++nt)
#pragma unroll
      for (int r = 0; r < 4; ++r) O[nt][r] *= alpha[r];
    short8 aP[2];
#pragma unroll
    for (int ks = 0; ks < 2; ++ks)
      aP[ks] = *(const short8*)&Ps[(wid * 16 + cl) * 72 + ks * 32 + kq];
#pragma unroll
    for (int nt = 0; nt < 4; ++nt)
#pragma unroll
      for (int ks = 0; ks < 2; ++ks) {
        const short8 bV = *(const short8*)&Vt[(nt * 16 + cl) * 72 + ks * 32 + kq];
        O[nt] = __builtin_amdgcn_mfma_f32_16x16x32_bf16(aP[ks], bV, O[nt], 0, 0, 0);
      }
  }

#pragma unroll
  for (int nt = 0; nt < 4; ++nt) {
    const int d = nt * 16 + cl;
#pragma unroll
    for (int r = 0; r < 4; ++r) {
      const int i = q0 + wid * 16 + rowg * 4 + r;
      ctx[(rowb + i) * 1024 + h * 64 + d] = f2b(O[nt][r] / l_i[r]);
    }
  }
}

// ---------------------------------------------------------------------------
// Residual + LayerNorm (unchanged from passing r5-r7).
// ---------------------------------------------------------------------------
template<int AF32, int BF32, int OF32>
__global__ __launch_bounds__(256) void ln_k(
    const void* __restrict__ a, const void* __restrict__ b,
    const float* __restrict__ g, const float* __restrict__ be,
    void* __restrict__ o)
{
  __shared__ float rbuf[8];
  const int tid = threadIdx.x;
  const size_t base = (size_t)blockIdx.x * 1024;
  const int lane = tid & 63, wid = tid >> 6;

  float xv[4], s = 0.f, sq = 0.f;
#pragma unroll
  for (int t = 0; t < 4; ++t) {
    const int c = tid + t * 256;
    const float av = AF32 ? ((const float*)a)[base + c]
                          : b2f(((const unsigned short*)a)[base + c]);
    const float bv = BF32 ? ((const float*)b)[base + c]
                          : b2f(((const unsigned short*)b)[base + c]);
    const float x = av + bv;
    xv[t] = x; s += x; sq += x * x;
  }
  for (int o2 = 1; o2 < 64; o2 <<= 1) { s += __shfl_xor(s, o2, 64); sq += __shfl_xor(sq, o2, 64); }
  if (lane == 0) { rbuf[wid] = s; rbuf[wid + 4] = sq; }
  __syncthreads();
  s  = rbuf[0] + rbuf[1] + rbuf[2] + rbuf[3];
  sq = rbuf[4] + rbuf[5] + rbuf[6] + rbuf[7];
  const float mean = s * (1.0f / 1024.f);
  const float var = sq * (1.0f / 1024.f) - mean * mean;
  const float rstd = rsqrtf(var + 1e-5f);
#pragma unroll
  for (int t = 0; t < 4; ++t) {
    const int c = tid + t * 256;
    const float y = (xv[t] - mean) * rstd * g[c] + be[c];
    if (OF32) ((float*)o)[base + c] = y;
    else      ((unsigned short*)o)[base + c] = f2b(y);
  }
}

// ---------------------------------------------------------------------------
extern "C" void kernel_launch(void* const* d_in, const int* in_sizes, int n_in,
                              void* d_out, int out_size, void* d_ws, size_t ws_size,
                              hipStream_t stream)
{
  (void)in_sizes; (void)n_in; (void)out_size; (void)ws_size;
  const float* src   = (const float*)d_in[0];
  const float* w_in  = (const float*)d_in[1];
  const float* b_in  = (const float*)d_in[2];
  const float* w_out = (const float*)d_in[3];
  const float* b_out = (const float*)d_in[4];
  const float* w1    = (const float*)d_in[5];
  const float* b1    = (const float*)d_in[6];
  const float* w2    = (const float*)d_in[7];
  const float* b2    = (const float*)d_in[8];
  const float* g1    = (const float*)d_in[9];
  const float* be1   = (const float*)d_in[10];
  const float* g2    = (const float*)d_in[11];
  const float* be2   = (const float*)d_in[12];

  char* ws = (char*)d_ws;
  unsigned short* qkv   = (unsigned short*)(ws);                 // [0, 25165824)
  unsigned short* ctx   = (unsigned short*)(ws + 25165824);      // [25165824, 33554432)
  unsigned short* attnb = (unsigned short*)(ws + 33554432);      // [33554432, 41943040)
  unsigned short* x1b   = (unsigned short*)(ws);                 // reuse qkv [0, 8388608)
  unsigned short* ff1   = (unsigned short*)(ws + 8388608);       // [8388608, 41943040)
  unsigned short* wslot = (unsigned short*)(ws + 41943040);      // [41943040, 50331648)
  float*          outf  = (float*)d_out;

  // 1) convert in_proj_w -> bf16; QKV projection -> bf16 qkv
  conv_k<<<dim3(1536), 256, 0, stream>>>(w_in, wslot, 3145728);
  gemm128<0, 1, 0><<<dim3(24, 32), 256, 0, stream>>>(src, wslot, b_in, qkv, 4096, 3072, 1024);
  // 2) banded MFMA flash attention -> bf16 ctx
  attn_mfma<<<dim3(1024), 256, 0, stream>>>(qkv, ctx);
  // 3) convert out_w; output projection (N=1024 -> gemm64, 512 blocks)
  conv_k<<<dim3(512), 256, 0, stream>>>(w_out, wslot, 1048576);
  gemm64<0><<<dim3(8, 64), 256, 0, stream>>>(ctx, wslot, b_out, attnb, 4096, 1024, 1024);
  // 4) LN1(src f32 + attnb bf16) -> bf16 x1b
  ln_k<1, 0, 0><<<dim3(4096), 256, 0, stream>>>(src, attnb, g1, be1, x1b);
  // 5) convert lin1_w; FF1 + ReLU -> bf16 ff1
  conv_k<<<dim3(2048), 256, 0, stream>>>(w1, wslot, 4194304);
  gemm128<1, 0, 0><<<dim3(32, 32), 256, 0, stream>>>(x1b, wslot, b1, ff1, 4096, 4096, 1024);
  // 6) convert lin2_w; FF2 (N=1024 -> gemm64, 512 blocks) -> f32 into d_out
  conv_k<<<dim3(2048), 256, 0, stream>>>(w2, wslot, 4194304);
  gemm64<1><<<dim3(8, 64), 256, 0, stream>>>(ff1, wslot, b2, outf, 4096, 1024, 4096);
  // 7) LN2(x1b bf16 + d_out f32) -> f32 d_out (in-place, per-row safe)
  ln_k<0, 1, 1><<<dim3(4096), 256, 0, stream>>>(x1b, outf, g2, be2, outf);
}

// Round 9
// 350.776 us; speedup vs baseline: 3.9866x; 1.0529x over previous
//
#include <hip/hip_runtime.h>
#include <cstdint>
#include <cstddef>

// ---------------------------------------------------------------------------
// RestrictedTransformerEncoderLayer on MI355X (gfx950)  — ROUND 9
// B=2, L=2048, E=1024, H=16, D=64, FF=4096, WIN=128.
// External I/O f32; intermediates bf16; output f32.
// R9: gemm64 -> BK=64 (16 MFMA/barrier, m97-level amortization, 24KB LDS,
// 2 blocks/CU). src pre-converted to bf16 (QKV staging fully async).
// Workspace (peak 50.33 MB):
//   srcb/x1b bf16 [0,        8388608)   (LN1 writes x1b in-place over srcb)
//   qkv  bf16     [8388608,  33554432)  dead after attn
//   ctx  bf16     [33554432, 41943040)  dead after out-proj
//   attnb bf16    [8388608,  16777216)  (reuse qkv)  dead after LN1
//   ff1  bf16     [8388608,  41943040)
//   wslot bf16    [41943040, 50331648)  converted weight (serial reuse)
// ---------------------------------------------------------------------------

typedef __attribute__((ext_vector_type(8))) short short8;   // 8 x bf16 MFMA frag
typedef __attribute__((ext_vector_type(4))) float f32x4;    // MFMA accumulator

__device__ __forceinline__ float b2f(unsigned short u) {
  union { unsigned int i; float f; } x; x.i = ((unsigned int)u) << 16; return x.f;
}
__device__ __forceinline__ unsigned short f2b(float f) {
  union { float f; unsigned int i; } x; x.f = f;
  unsigned int i = x.i;
  unsigned int r = (i + 0x7FFFu + ((i >> 16) & 1u)) >> 16;  // RNE
  return (unsigned short)r;
}
__device__ __forceinline__ uint4 pack8(float4 f0, float4 f1) {
  uint4 r;
  r.x = (unsigned)f2b(f0.x) | ((unsigned)f2b(f0.y) << 16);
  r.y = (unsigned)f2b(f0.z) | ((unsigned)f2b(f0.w) << 16);
  r.z = (unsigned)f2b(f1.x) | ((unsigned)f2b(f1.y) << 16);
  r.w = (unsigned)f2b(f1.z) | ((unsigned)f2b(f1.w) << 16);
  return r;
}

// async global->LDS, 16B/lane; LDS base wave-uniform, lanes write base+lane*16
__device__ __forceinline__ void gl_lds16(const unsigned short* g, unsigned short* l) {
  __builtin_amdgcn_global_load_lds(
      (const __attribute__((address_space(1))) unsigned int*)g,
      (__attribute__((address_space(3))) unsigned int*)l, 16, 0, 0);
}

// ---------------------------------------------------------------------------
// f32 -> bf16 convert
// ---------------------------------------------------------------------------
__global__ __launch_bounds__(256) void conv_k(
    const float* __restrict__ in, unsigned short* __restrict__ out, int n)
{
  const int i = (blockIdx.x * 256 + threadIdx.x) * 8;
  if (i < n) {
    const float4 f0 = *(const float4*)(in + i);
    const float4 f1 = *(const float4*)(in + i + 4);
    *(uint4*)(out + i) = pack8(f0, f1);
  }
}

// ---------------------------------------------------------------------------
// GEMM 128x128 tile, BK=32 (unchanged from passing r7/r8; AF32 path unused).
// LDS swizzle: slot (r,s) holds chunk c=(s+(r>>1))&3; reader s=(kg-(r>>1))&3.
// ---------------------------------------------------------------------------
template<int RELU, int OUT32>
__global__ __launch_bounds__(256) void gemm128(
    const unsigned short* __restrict__ A, const unsigned short* __restrict__ Wb,
    const float* __restrict__ bias, void* __restrict__ out,
    int M, int N, int K)
{
  __shared__ unsigned short As[128 * 32];
  __shared__ unsigned short Bs[128 * 32];

  const int tid = threadIdx.x;
  const int lane = tid & 63, wid = tid >> 6;
  const int m0 = blockIdx.y * 128, n0 = blockIdx.x * 128;

  const int r0 = tid >> 2, s0 = tid & 3;
  const int c0 = (s0 + (r0 >> 1)) & 3;
  const int r1 = r0 + 64;

  const unsigned short* gW0 = Wb + (size_t)(n0 + r0) * K + c0 * 8;
  const unsigned short* gW1 = Wb + (size_t)(n0 + r1) * K + c0 * 8;
  const unsigned short* gA0 = A + (size_t)(m0 + r0) * K + c0 * 8;
  const unsigned short* gA1 = A + (size_t)(m0 + r1) * K + c0 * 8;

  const int cl = lane & 15;
  const int kg = lane >> 4;
  const int msub = (wid >> 1) * 64, nsub = (wid & 1) * 64;
  int aoffs[4], boffs[4];
#pragma unroll
  for (int t = 0; t < 4; ++t) {
    const int ar = msub + t * 16 + cl;
    aoffs[t] = ar * 32 + ((kg - (ar >> 1)) & 3) * 8;
    const int br = nsub + t * 16 + cl;
    boffs[t] = br * 32 + ((kg - (br >> 1)) & 3) * 8;
  }

  f32x4 acc[4][4];
#pragma unroll
  for (int i = 0; i < 4; ++i)
#pragma unroll
    for (int j = 0; j < 4; ++j) acc[i][j] = (f32x4){0.f, 0.f, 0.f, 0.f};

  const int steps = K >> 5;
  for (int s = 0; s < steps; ++s) {
    gl_lds16(gA0, &As[wid * 512]);
    gl_lds16(gA1, &As[2048 + wid * 512]);
    gl_lds16(gW0, &Bs[wid * 512]);
    gl_lds16(gW1, &Bs[2048 + wid * 512]);
    gA0 += 32; gA1 += 32; gW0 += 32; gW1 += 32;
    __syncthreads();

    short8 af[4], bf[4];
#pragma unroll
    for (int t = 0; t < 4; ++t) af[t] = *(const short8*)&As[aoffs[t]];
#pragma unroll
    for (int t = 0; t < 4; ++t) bf[t] = *(const short8*)&Bs[boffs[t]];
#pragma unroll
    for (int mt = 0; mt < 4; ++mt)
#pragma unroll
      for (int nt = 0; nt < 4; ++nt)
        acc[mt][nt] = __builtin_amdgcn_mfma_f32_16x16x32_bf16(af[mt], bf[nt], acc[mt][nt], 0, 0, 0);
    __syncthreads();
  }

#pragma unroll
  for (int nt = 0; nt < 4; ++nt) {
    const int col = n0 + nsub + nt * 16 + cl;
    const float bvs = bias[col];
#pragma unroll
    for (int mt = 0; mt < 4; ++mt) {
#pragma unroll
      for (int r = 0; r < 4; ++r) {
        const int grow = m0 + msub + mt * 16 + kg * 4 + r;
        float v = acc[mt][nt][r] + bvs;
        if (RELU) v = fmaxf(v, 0.f);
        if (OUT32) ((float*)out)[(size_t)grow * N + col] = v;
        else       ((unsigned short*)out)[(size_t)grow * N + col] = f2b(v);
      }
    }
  }
}

// ---------------------------------------------------------------------------
// GEMM 64x128 tile, BK=64 — N=1024 shapes (grid 512 = 2 blocks/CU).
// 16 MFMA + 6 async 16B loads per thread per barrier. 24 KB LDS.
// Swizzle (8 chunks/row): slot s of row r holds chunk (s+(r>>1))&7;
// reader for chunk c uses slot (c-(r>>1))&7 -> 2-way max (free).
// ---------------------------------------------------------------------------
template<int OUT32>
__global__ __launch_bounds__(256) void gemm64(
    const unsigned short* __restrict__ A, const unsigned short* __restrict__ Wb,
    const float* __restrict__ bias, void* __restrict__ out,
    int M, int N, int K)
{
  __shared__ unsigned short As[64 * 64];    // 8 KB
  __shared__ unsigned short Bs[128 * 64];   // 16 KB

  const int tid = threadIdx.x;
  const int lane = tid & 63, wid = tid >> 6;
  const int m0 = blockIdx.y * 64, n0 = blockIdx.x * 128;

  // staging: A = 512 slots (wave w: chunks 2w,2w+1), B = 1024 (wave w: 4w..4w+3)
  const unsigned short* gA[2];
  const unsigned short* gW[4];
  int ldsA[2], ldsB[4];
#pragma unroll
  for (int i = 0; i < 2; ++i) {
    const int sl = wid * 128 + i * 64 + lane;
    const int r = sl >> 3, s = sl & 7, c = (s + (r >> 1)) & 7;
    gA[i] = A + (size_t)(m0 + r) * K + c * 8;
    ldsA[i] = (wid * 128 + i * 64) * 8;
  }
#pragma unroll
  for (int i = 0; i < 4; ++i) {
    const int sl = wid * 256 + i * 64 + lane;
    const int r = sl >> 3, s = sl & 7, c = (s + (r >> 1)) & 7;
    gW[i] = Wb + (size_t)(n0 + r) * K + c * 8;
    ldsB[i] = (wid * 256 + i * 64) * 8;
  }

  const int cl = lane & 15;
  const int kg = lane >> 4;
  int aoff[4][2], boff[2][2];
#pragma unroll
  for (int t = 0; t < 4; ++t) {
    const int ar = t * 16 + cl;
#pragma unroll
    for (int ks = 0; ks < 2; ++ks)
      aoff[t][ks] = ar * 64 + ((ks * 4 + kg - (ar >> 1)) & 7) * 8;
  }
#pragma unroll
  for (int t = 0; t < 2; ++t) {
    const int br = wid * 32 + t * 16 + cl;
#pragma unroll
    for (int ks = 0; ks < 2; ++ks)
      boff[t][ks] = br * 64 + ((ks * 4 + kg - (br >> 1)) & 7) * 8;
  }

  f32x4 acc[4][2];
#pragma unroll
  for (int i = 0; i < 4; ++i)
#pragma unroll
    for (int j = 0; j < 2; ++j) acc[i][j] = (f32x4){0.f, 0.f, 0.f, 0.f};

  const int steps = K >> 6;
  for (int s = 0; s < steps; ++s) {
#pragma unroll
    for (int i = 0; i < 2; ++i) { gl_lds16(gA[i], &As[ldsA[i]]); gA[i] += 64; }
#pragma unroll
    for (int i = 0; i < 4; ++i) { gl_lds16(gW[i], &Bs[ldsB[i]]); gW[i] += 64; }
    __syncthreads();

    short8 af[4][2], bf[2][2];
#pragma unroll
    for (int t = 0; t < 4; ++t)
#pragma unroll
      for (int ks = 0; ks < 2; ++ks) af[t][ks] = *(const short8*)&As[aoff[t][ks]];
#pragma unroll
    for (int t = 0; t < 2; ++t)
#pragma unroll
      for (int ks = 0; ks < 2; ++ks) bf[t][ks] = *(const short8*)&Bs[boff[t][ks]];
#pragma unroll
    for (int mt = 0; mt < 4; ++mt)
#pragma unroll
      for (int nt = 0; nt < 2; ++nt)
#pragma unroll
        for (int ks = 0; ks < 2; ++ks)
          acc[mt][nt] = __builtin_amdgcn_mfma_f32_16x16x32_bf16(af[mt][ks], bf[nt][ks], acc[mt][nt], 0, 0, 0);
    __syncthreads();
  }

#pragma unroll
  for (int nt = 0; nt < 2; ++nt) {
    const int col = n0 + wid * 32 + nt * 16 + cl;
    const float bvs = bias[col];
#pragma unroll
    for (int mt = 0; mt < 4; ++mt) {
#pragma unroll
      for (int r = 0; r < 4; ++r) {
        const int grow = m0 + mt * 16 + kg * 4 + r;
        const float v = acc[mt][nt][r] + bvs;
        if (OUT32) ((float*)out)[(size_t)grow * N + col] = v;
        else       ((unsigned short*)out)[(size_t)grow * N + col] = f2b(v);
      }
    }
  }
}

// ---------------------------------------------------------------------------
// MFMA flash attention (unchanged from passing r6-r8).
// ---------------------------------------------------------------------------
__global__ __launch_bounds__(256) void attn_mfma(
    const unsigned short* __restrict__ qkv, unsigned short* __restrict__ ctx)
{
  __shared__ unsigned short Ks[64 * 72];
  __shared__ unsigned short Vt[64 * 72];
  __shared__ unsigned short Ps[64 * 72];

  const int tid = threadIdx.x;
  const int bid = blockIdx.x;
  const int qt = bid & 31, h = (bid >> 5) & 15, b = bid >> 9;
  const int q0 = qt * 64;
  const int wstart = max(0, q0 - 128);
  const int wend = min(2048, q0 + 64 + 128);
  const int ntile = (wend - wstart + 63) >> 6;
  const size_t rowb = (size_t)b * 2048;

  const int lane = tid & 63, wid = tid >> 6;
  const int cl = lane & 15;
  const int kq = (lane >> 4) * 8;
  const int rowg = lane >> 4;

  short8 aQ[2];
#pragma unroll
  for (int ks = 0; ks < 2; ++ks)
    aQ[ks] = *(const short8*)(qkv + (rowb + q0 + wid * 16 + cl) * 3072 + h * 64 + ks * 32 + kq);

  float m_i[4], l_i[4];
  f32x4 O[4];
#pragma unroll
  for (int r = 0; r < 4; ++r) { m_i[r] = -1.0e30f; l_i[r] = 0.f; }
#pragma unroll
  for (int nt = 0; nt < 4; ++nt) O[nt] = (f32x4){0.f, 0.f, 0.f, 0.f};

  for (int t = 0; t < ntile; ++t) {
    const int jbase = wstart + t * 64;
    __syncthreads();
    for (int idx = tid; idx < 512; idx += 256) {
      const int r = idx >> 3, c = idx & 7;
      const int jg = jbase + r;
      uint4 kv = {0u, 0u, 0u, 0u}, vv = {0u, 0u, 0u, 0u};
      if (jg < wend) {
        const size_t base = (rowb + jg) * 3072 + h * 64 + c * 8;
        kv = *(const uint4*)(qkv + base + 1024);
        vv = *(const uint4*)(qkv + base + 2048);
      }
      *(uint4*)&Ks[r * 72 + c * 8] = kv;
      const unsigned short* vs = (const unsigned short*)&vv;
#pragma unroll
      for (int ii = 0; ii < 8; ++ii) Vt[(c * 8 + ii) * 72 + r] = vs[ii];
    }
    __syncthreads();

    f32x4 S[4];
#pragma unroll
    for (int nt = 0; nt < 4; ++nt) S[nt] = (f32x4){0.f, 0.f, 0.f, 0.f};
#pragma unroll
    for (int nt = 0; nt < 4; ++nt)
#pragma unroll
      for (int ks = 0; ks < 2; ++ks) {
        const short8 bK = *(const short8*)&Ks[(nt * 16 + cl) * 72 + ks * 32 + kq];
        S[nt] = __builtin_amdgcn_mfma_f32_16x16x32_bf16(aQ[ks], bK, S[nt], 0, 0, 0);
      }

    float sc[4][4];
#pragma unroll
    for (int nt = 0; nt < 4; ++nt) {
      const int jg = jbase + nt * 16 + cl;
#pragma unroll
      for (int r = 0; r < 4; ++r) {
        const int i = q0 + wid * 16 + rowg * 4 + r;
        const bool v = (jg < wend) && (jg >= i - 128) && (jg <= i + 128);
        sc[nt][r] = v ? S[nt][r] * 0.125f : -1.0e30f;
      }
    }

    float alpha[4], p[4][4];
#pragma unroll
    for (int r = 0; r < 4; ++r) {
      float tm = fmaxf(fmaxf(sc[0][r], sc[1][r]), fmaxf(sc[2][r], sc[3][r]));
      tm = fmaxf(tm, __shfl_xor(tm, 1, 64));
      tm = fmaxf(tm, __shfl_xor(tm, 2, 64));
      tm = fmaxf(tm, __shfl_xor(tm, 4, 64));
      tm = fmaxf(tm, __shfl_xor(tm, 8, 64));
      const float mn = fmaxf(m_i[r], tm);
      alpha[r] = __expf(m_i[r] - mn);
      m_i[r] = mn;
      float ps = 0.f;
#pragma unroll
      for (int nt = 0; nt < 4; ++nt) { p[nt][r] = __expf(sc[nt][r] - mn); ps += p[nt][r]; }
      ps += __shfl_xor(ps, 1, 64);
      ps += __shfl_xor(ps, 2, 64);
      ps += __shfl_xor(ps, 4, 64);
      ps += __shfl_xor(ps, 8, 64);
      l_i[r] = l_i[r] * alpha[r] + ps;
    }

#pragma unroll
    for (int nt = 0; nt < 4; ++nt)
#pragma unroll
      for (int r = 0; r < 4; ++r)
        Ps[(wid * 16 + rowg * 4 + r) * 72 + nt * 16 + cl] = f2b(p[nt][r]);
    __syncthreads();

#pragma unroll
    for (int nt = 0; nt < 4; ++nt)
#pragma unroll
      for (int r = 0; r < 4; ++r) O[nt][r] *= alpha[r];
    short8 aP[2];
#pragma unroll
    for (int ks = 0; ks < 2; ++ks)
      aP[ks] = *(const short8*)&Ps[(wid * 16 + cl) * 72 + ks * 32 + kq];
#pragma unroll
    for (int nt = 0; nt < 4; ++nt)
#pragma unroll
      for (int ks = 0; ks < 2; ++ks) {
        const short8 bV = *(const short8*)&Vt[(nt * 16 + cl) * 72 + ks * 32 + kq];
        O[nt] = __builtin_amdgcn_mfma_f32_16x16x32_bf16(aP[ks], bV, O[nt], 0, 0, 0);
      }
  }

#pragma unroll
  for (int nt = 0; nt < 4; ++nt) {
    const int d = nt * 16 + cl;
#pragma unroll
    for (int r = 0; r < 4; ++r) {
      const int i = q0 + wid * 16 + rowg * 4 + r;
      ctx[(rowb + i) * 1024 + h * 64 + d] = f2b(O[nt][r] / l_i[r]);
    }
  }
}

// ---------------------------------------------------------------------------
// Residual + LayerNorm (unchanged). In-place safe per-row.
// ---------------------------------------------------------------------------
template<int AF32, int BF32, int OF32>
__global__ __launch_bounds__(256) void ln_k(
    const void* __restrict__ a, const void* __restrict__ b,
    const float* __restrict__ g, const float* __restrict__ be,
    void* __restrict__ o)
{
  __shared__ float rbuf[8];
  const int tid = threadIdx.x;
  const size_t base = (size_t)blockIdx.x * 1024;
  const int lane = tid & 63, wid = tid >> 6;

  float xv[4], s = 0.f, sq = 0.f;
#pragma unroll
  for (int t = 0; t < 4; ++t) {
    const int c = tid + t * 256;
    const float av = AF32 ? ((const float*)a)[base + c]
                          : b2f(((const unsigned short*)a)[base + c]);
    const float bv = BF32 ? ((const float*)b)[base + c]
                          : b2f(((const unsigned short*)b)[base + c]);
    const float x = av + bv;
    xv[t] = x; s += x; sq += x * x;
  }
  for (int o2 = 1; o2 < 64; o2 <<= 1) { s += __shfl_xor(s, o2, 64); sq += __shfl_xor(sq, o2, 64); }
  if (lane == 0) { rbuf[wid] = s; rbuf[wid + 4] = sq; }
  __syncthreads();
  s  = rbuf[0] + rbuf[1] + rbuf[2] + rbuf[3];
  sq = rbuf[4] + rbuf[5] + rbuf[6] + rbuf[7];
  const float mean = s * (1.0f / 1024.f);
  const float var = sq * (1.0f / 1024.f) - mean * mean;
  const float rstd = rsqrtf(var + 1e-5f);
#pragma unroll
  for (int t = 0; t < 4; ++t) {
    const int c = tid + t * 256;
    const float y = (xv[t] - mean) * rstd * g[c] + be[c];
    if (OF32) ((float*)o)[base + c] = y;
    else      ((unsigned short*)o)[base + c] = f2b(y);
  }
}

// ---------------------------------------------------------------------------
extern "C" void kernel_launch(void* const* d_in, const int* in_sizes, int n_in,
                              void* d_out, int out_size, void* d_ws, size_t ws_size,
                              hipStream_t stream)
{
  (void)in_sizes; (void)n_in; (void)out_size; (void)ws_size;
  const float* src   = (const float*)d_in[0];
  const float* w_in  = (const float*)d_in[1];
  const float* b_in  = (const float*)d_in[2];
  const float* w_out = (const float*)d_in[3];
  const float* b_out = (const float*)d_in[4];
  const float* w1    = (const float*)d_in[5];
  const float* b1    = (const float*)d_in[6];
  const float* w2    = (const float*)d_in[7];
  const float* b2    = (const float*)d_in[8];
  const float* g1    = (const float*)d_in[9];
  const float* be1   = (const float*)d_in[10];
  const float* g2    = (const float*)d_in[11];
  const float* be2   = (const float*)d_in[12];

  char* ws = (char*)d_ws;
  unsigned short* srcb  = (unsigned short*)(ws);                 // [0, 8388608)
  unsigned short* x1b   = srcb;                                  // in-place over srcb
  unsigned short* qkv   = (unsigned short*)(ws + 8388608);       // [8388608, 33554432)
  unsigned short* ctx   = (unsigned short*)(ws + 33554432);      // [33554432, 41943040)
  unsigned short* attnb = (unsigned short*)(ws + 8388608);       // reuse qkv head
  unsigned short* ff1   = (unsigned short*)(ws + 8388608);       // [8388608, 41943040)
  unsigned short* wslot = (unsigned short*)(ws + 41943040);      // [41943040, 50331648)
  float*          outf  = (float*)d_out;

  // 0) convert src -> bf16 srcb
  conv_k<<<dim3(2048), 256, 0, stream>>>(src, srcb, 4194304);
  // 1) convert in_proj_w; QKV projection -> bf16 qkv (pure async staging)
  conv_k<<<dim3(1536), 256, 0, stream>>>(w_in, wslot, 3145728);
  gemm128<0, 0><<<dim3(24, 32), 256, 0, stream>>>(srcb, wslot, b_in, qkv, 4096, 3072, 1024);
  // 2) banded MFMA flash attention -> bf16 ctx
  attn_mfma<<<dim3(1024), 256, 0, stream>>>(qkv, ctx);
  // 3) convert out_w; output projection (gemm64 BK=64) -> bf16 attnb
  conv_k<<<dim3(512), 256, 0, stream>>>(w_out, wslot, 1048576);
  gemm64<0><<<dim3(8, 64), 256, 0, stream>>>(ctx, wslot, b_out, attnb, 4096, 1024, 1024);
  // 4) LN1(srcb bf16 + attnb bf16) -> bf16 x1b (in-place over srcb)
  ln_k<0, 0, 0><<<dim3(4096), 256, 0, stream>>>(srcb, attnb, g1, be1, x1b);
  // 5) convert lin1_w; FF1 + ReLU -> bf16 ff1
  conv_k<<<dim3(2048), 256, 0, stream>>>(w1, wslot, 4194304);
  gemm128<1, 0><<<dim3(32, 32), 256, 0, stream>>>(x1b, wslot, b1, ff1, 4096, 4096, 1024);
  // 6) convert lin2_w; FF2 (gemm64 BK=64) -> f32 into d_out
  conv_k<<<dim3(2048), 256, 0, stream>>>(w2, wslot, 4194304);
  gemm64<1><<<dim3(8, 64), 256, 0, stream>>>(ff1, wslot, b2, outf, 4096, 1024, 4096);
  // 7) LN2(x1b bf16 + d_out f32) -> f32 d_out (in-place, per-row safe)
  ln_k<0, 1, 1><<<dim3(4096), 256, 0, stream>>>(x1b, outf, g2, be2, outf);
}

// Round 10
// 332.166 us; speedup vs baseline: 4.2100x; 1.0560x over previous
//
#include <hip/hip_runtime.h>
#include <cstdint>
#include <cstddef>

// ---------------------------------------------------------------------------
// RestrictedTransformerEncoderLayer on MI355X (gfx950)  — ROUND 10
// B=2, L=2048, E=1024, H=16, D=64, FF=4096, WIN=128.
// External I/O f32; intermediates bf16; output f32.
// R10: (1) gemm64 swizzle rotation r>>1 -> r (BK=64 rows are 128B = one full
// bank line; r>>1 paired lanes onto the same bank group -> 6.3e6 conflicts).
// (2) gemm128 BK 32->64 with the same r-rotation (32KB LDS, 32 MFMA/barrier).
// Workspace (peak 50.33 MB):
//   srcb/x1b bf16 [0,        8388608)   (LN1 in-place over srcb)
//   qkv  bf16     [8388608,  33554432)  dead after attn
//   ctx  bf16     [33554432, 41943040)  dead after out-proj
//   attnb bf16    [8388608,  16777216)  (reuse qkv)  dead after LN1
//   ff1  bf16     [8388608,  41943040)
//   wslot bf16    [41943040, 50331648)  converted weight (serial reuse)
// ---------------------------------------------------------------------------

typedef __attribute__((ext_vector_type(8))) short short8;   // 8 x bf16 MFMA frag
typedef __attribute__((ext_vector_type(4))) float f32x4;    // MFMA accumulator

__device__ __forceinline__ float b2f(unsigned short u) {
  union { unsigned int i; float f; } x; x.i = ((unsigned int)u) << 16; return x.f;
}
__device__ __forceinline__ unsigned short f2b(float f) {
  union { float f; unsigned int i; } x; x.f = f;
  unsigned int i = x.i;
  unsigned int r = (i + 0x7FFFu + ((i >> 16) & 1u)) >> 16;  // RNE
  return (unsigned short)r;
}
__device__ __forceinline__ uint4 pack8(float4 f0, float4 f1) {
  uint4 r;
  r.x = (unsigned)f2b(f0.x) | ((unsigned)f2b(f0.y) << 16);
  r.y = (unsigned)f2b(f0.z) | ((unsigned)f2b(f0.w) << 16);
  r.z = (unsigned)f2b(f1.x) | ((unsigned)f2b(f1.y) << 16);
  r.w = (unsigned)f2b(f1.z) | ((unsigned)f2b(f1.w) << 16);
  return r;
}

// async global->LDS, 16B/lane; LDS base wave-uniform, lanes write base+lane*16
__device__ __forceinline__ void gl_lds16(const unsigned short* g, unsigned short* l) {
  __builtin_amdgcn_global_load_lds(
      (const __attribute__((address_space(1))) unsigned int*)g,
      (__attribute__((address_space(3))) unsigned int*)l, 16, 0, 0);
}

// ---------------------------------------------------------------------------
// f32 -> bf16 convert
// ---------------------------------------------------------------------------
__global__ __launch_bounds__(256) void conv_k(
    const float* __restrict__ in, unsigned short* __restrict__ out, int n)
{
  const int i = (blockIdx.x * 256 + threadIdx.x) * 8;
  if (i < n) {
    const float4 f0 = *(const float4*)(in + i);
    const float4 f1 = *(const float4*)(in + i + 4);
    *(uint4*)(out + i) = pack8(f0, f1);
  }
}

// ---------------------------------------------------------------------------
// GEMM 128x128 tile, BK=64: out[M,N] = A[M,K] @ W[N,K]^T + bias. bf16 in.
// Swizzle (8x16B chunks/row, 128B rows): slot s of row r holds chunk
// c=(s+r)&7; reader for chunk c uses slot (c-r)&7. Within any 8 consecutive
// cl lanes slots take all 8 values -> all 32 banks once per phase (free).
// 32 MFMA + 8 async loads per thread per barrier. 32 KB LDS.
// ---------------------------------------------------------------------------
template<int RELU, int OUT32>
__global__ __launch_bounds__(256) void gemm128(
    const unsigned short* __restrict__ A, const unsigned short* __restrict__ Wb,
    const float* __restrict__ bias, void* __restrict__ out,
    int M, int N, int K)
{
  __shared__ unsigned short As[128 * 64];   // 16 KB
  __shared__ unsigned short Bs[128 * 64];   // 16 KB

  const int tid = threadIdx.x;
  const int lane = tid & 63, wid = tid >> 6;
  const int m0 = blockIdx.y * 128, n0 = blockIdx.x * 128;

  // staging: 1024 slots each; wave w covers slots [w*256, +256) = rows w*32..+31
  const unsigned short* gA[4];
  const unsigned short* gW[4];
  int ldsO[4];
#pragma unroll
  for (int i = 0; i < 4; ++i) {
    const int sl = wid * 256 + i * 64 + lane;
    const int r = sl >> 3, s = sl & 7, c = (s + r) & 7;
    gA[i] = A + (size_t)(m0 + r) * K + c * 8;
    gW[i] = Wb + (size_t)(n0 + r) * K + c * 8;
    ldsO[i] = (wid * 256 + i * 64) * 8;
  }

  const int cl = lane & 15;
  const int kg = lane >> 4;
  const int msub = (wid >> 1) * 64, nsub = (wid & 1) * 64;
  int aoff[4][2], boff[4][2];
#pragma unroll
  for (int t = 0; t < 4; ++t) {
    const int ar = msub + t * 16 + cl;
    const int br = nsub + t * 16 + cl;
#pragma unroll
    for (int ks = 0; ks < 2; ++ks) {
      aoff[t][ks] = ar * 64 + ((ks * 4 + kg - ar) & 7) * 8;
      boff[t][ks] = br * 64 + ((ks * 4 + kg - br) & 7) * 8;
    }
  }

  f32x4 acc[4][4];
#pragma unroll
  for (int i = 0; i < 4; ++i)
#pragma unroll
    for (int j = 0; j < 4; ++j) acc[i][j] = (f32x4){0.f, 0.f, 0.f, 0.f};

  const int steps = K >> 6;
  for (int s = 0; s < steps; ++s) {
#pragma unroll
    for (int i = 0; i < 4; ++i) { gl_lds16(gA[i], &As[ldsO[i]]); gA[i] += 64; }
#pragma unroll
    for (int i = 0; i < 4; ++i) { gl_lds16(gW[i], &Bs[ldsO[i]]); gW[i] += 64; }
    __syncthreads();

    short8 af[4][2], bf[4][2];
#pragma unroll
    for (int t = 0; t < 4; ++t)
#pragma unroll
      for (int ks = 0; ks < 2; ++ks) {
        af[t][ks] = *(const short8*)&As[aoff[t][ks]];
        bf[t][ks] = *(const short8*)&Bs[boff[t][ks]];
      }
#pragma unroll
    for (int mt = 0; mt < 4; ++mt)
#pragma unroll
      for (int nt = 0; nt < 4; ++nt)
#pragma unroll
        for (int ks = 0; ks < 2; ++ks)
          acc[mt][nt] = __builtin_amdgcn_mfma_f32_16x16x32_bf16(af[mt][ks], bf[nt][ks], acc[mt][nt], 0, 0, 0);
    __syncthreads();
  }

  // epilogue: C/D mapping col = cl, row = kg*4 + r  [m89-verified]
#pragma unroll
  for (int nt = 0; nt < 4; ++nt) {
    const int col = n0 + nsub + nt * 16 + cl;
    const float bvs = bias[col];
#pragma unroll
    for (int mt = 0; mt < 4; ++mt) {
#pragma unroll
      for (int r = 0; r < 4; ++r) {
        const int grow = m0 + msub + mt * 16 + kg * 4 + r;
        float v = acc[mt][nt][r] + bvs;
        if (RELU) v = fmaxf(v, 0.f);
        if (OUT32) ((float*)out)[(size_t)grow * N + col] = v;
        else       ((unsigned short*)out)[(size_t)grow * N + col] = f2b(v);
      }
    }
  }
}

// ---------------------------------------------------------------------------
// GEMM 64x128 tile, BK=64 — N=1024 shapes (grid 512 = 2 blocks/CU). 24 KB LDS.
// Same r-rotation swizzle (conflict-free).
// ---------------------------------------------------------------------------
template<int OUT32>
__global__ __launch_bounds__(256) void gemm64(
    const unsigned short* __restrict__ A, const unsigned short* __restrict__ Wb,
    const float* __restrict__ bias, void* __restrict__ out,
    int M, int N, int K)
{
  __shared__ unsigned short As[64 * 64];    // 8 KB
  __shared__ unsigned short Bs[128 * 64];   // 16 KB

  const int tid = threadIdx.x;
  const int lane = tid & 63, wid = tid >> 6;
  const int m0 = blockIdx.y * 64, n0 = blockIdx.x * 128;

  const unsigned short* gA[2];
  const unsigned short* gW[4];
  int ldsA[2], ldsB[4];
#pragma unroll
  for (int i = 0; i < 2; ++i) {
    const int sl = wid * 128 + i * 64 + lane;
    const int r = sl >> 3, s = sl & 7, c = (s + r) & 7;
    gA[i] = A + (size_t)(m0 + r) * K + c * 8;
    ldsA[i] = (wid * 128 + i * 64) * 8;
  }
#pragma unroll
  for (int i = 0; i < 4; ++i) {
    const int sl = wid * 256 + i * 64 + lane;
    const int r = sl >> 3, s = sl & 7, c = (s + r) & 7;
    gW[i] = Wb + (size_t)(n0 + r) * K + c * 8;
    ldsB[i] = (wid * 256 + i * 64) * 8;
  }

  const int cl = lane & 15;
  const int kg = lane >> 4;
  int aoff[4][2], boff[2][2];
#pragma unroll
  for (int t = 0; t < 4; ++t) {
    const int ar = t * 16 + cl;
#pragma unroll
    for (int ks = 0; ks < 2; ++ks)
      aoff[t][ks] = ar * 64 + ((ks * 4 + kg - ar) & 7) * 8;
  }
#pragma unroll
  for (int t = 0; t < 2; ++t) {
    const int br = wid * 32 + t * 16 + cl;
#pragma unroll
    for (int ks = 0; ks < 2; ++ks)
      boff[t][ks] = br * 64 + ((ks * 4 + kg - br) & 7) * 8;
  }

  f32x4 acc[4][2];
#pragma unroll
  for (int i = 0; i < 4; ++i)
#pragma unroll
    for (int j = 0; j < 2; ++j) acc[i][j] = (f32x4){0.f, 0.f, 0.f, 0.f};

  const int steps = K >> 6;
  for (int s = 0; s < steps; ++s) {
#pragma unroll
    for (int i = 0; i < 2; ++i) { gl_lds16(gA[i], &As[ldsA[i]]); gA[i] += 64; }
#pragma unroll
    for (int i = 0; i < 4; ++i) { gl_lds16(gW[i], &Bs[ldsB[i]]); gW[i] += 64; }
    __syncthreads();

    short8 af[4][2], bf[2][2];
#pragma unroll
    for (int t = 0; t < 4; ++t)
#pragma unroll
      for (int ks = 0; ks < 2; ++ks) af[t][ks] = *(const short8*)&As[aoff[t][ks]];
#pragma unroll
    for (int t = 0; t < 2; ++t)
#pragma unroll
      for (int ks = 0; ks < 2; ++ks) bf[t][ks] = *(const short8*)&Bs[boff[t][ks]];
#pragma unroll
    for (int mt = 0; mt < 4; ++mt)
#pragma unroll
      for (int nt = 0; nt < 2; ++nt)
#pragma unroll
        for (int ks = 0; ks < 2; ++ks)
          acc[mt][nt] = __builtin_amdgcn_mfma_f32_16x16x32_bf16(af[mt][ks], bf[nt][ks], acc[mt][nt], 0, 0, 0);
    __syncthreads();
  }

#pragma unroll
  for (int nt = 0; nt < 2; ++nt) {
    const int col = n0 + wid * 32 + nt * 16 + cl;
    const float bvs = bias[col];
#pragma unroll
    for (int mt = 0; mt < 4; ++mt) {
#pragma unroll
      for (int r = 0; r < 4; ++r) {
        const int grow = m0 + mt * 16 + kg * 4 + r;
        const float v = acc[mt][nt][r] + bvs;
        if (OUT32) ((float*)out)[(size_t)grow * N + col] = v;
        else       ((unsigned short*)out)[(size_t)grow * N + col] = f2b(v);
      }
    }
  }
}

// ---------------------------------------------------------------------------
// MFMA flash attention (unchanged from passing r6-r9).
// ---------------------------------------------------------------------------
__global__ __launch_bounds__(256) void attn_mfma(
    const unsigned short* __restrict__ qkv, unsigned short* __restrict__ ctx)
{
  __shared__ unsigned short Ks[64 * 72];
  __shared__ unsigned short Vt[64 * 72];
  __shared__ unsigned short Ps[64 * 72];

  const int tid = threadIdx.x;
  const int bid = blockIdx.x;
  const int qt = bid & 31, h = (bid >> 5) & 15, b = bid >> 9;
  const int q0 = qt * 64;
  const int wstart = max(0, q0 - 128);
  const int wend = min(2048, q0 + 64 + 128);
  const int ntile = (wend - wstart + 63) >> 6;
  const size_t rowb = (size_t)b * 2048;

  const int lane = tid & 63, wid = tid >> 6;
  const int cl = lane & 15;
  const int kq = (lane >> 4) * 8;
  const int rowg = lane >> 4;

  short8 aQ[2];
#pragma unroll
  for (int ks = 0; ks < 2; ++ks)
    aQ[ks] = *(const short8*)(qkv + (rowb + q0 + wid * 16 + cl) * 3072 + h * 64 + ks * 32 + kq);

  float m_i[4], l_i[4];
  f32x4 O[4];
#pragma unroll
  for (int r = 0; r < 4; ++r) { m_i[r] = -1.0e30f; l_i[r] = 0.f; }
#pragma unroll
  for (int nt = 0; nt < 4; ++nt) O[nt] = (f32x4){0.f, 0.f, 0.f, 0.f};

  for (int t = 0; t < ntile; ++t) {
    const int jbase = wstart + t * 64;
    __syncthreads();
    for (int idx = tid; idx < 512; idx += 256) {
      const int r = idx >> 3, c = idx & 7;
      const int jg = jbase + r;
      uint4 kv = {0u, 0u, 0u, 0u}, vv = {0u, 0u, 0u, 0u};
      if (jg < wend) {
        const size_t base = (rowb + jg) * 3072 + h * 64 + c * 8;
        kv = *(const uint4*)(qkv + base + 1024);
        vv = *(const uint4*)(qkv + base + 2048);
      }
      *(uint4*)&Ks[r * 72 + c * 8] = kv;
      const unsigned short* vs = (const unsigned short*)&vv;
#pragma unroll
      for (int ii = 0; ii < 8; ++ii) Vt[(c * 8 + ii) * 72 + r] = vs[ii];
    }
    __syncthreads();

    f32x4 S[4];
#pragma unroll
    for (int nt = 0; nt < 4; ++nt) S[nt] = (f32x4){0.f, 0.f, 0.f, 0.f};
#pragma unroll
    for (int nt = 0; nt < 4; ++nt)
#pragma unroll
      for (int ks = 0; ks < 2; ++ks) {
        const short8 bK = *(const short8*)&Ks[(nt * 16 + cl) * 72 + ks * 32 + kq];
        S[nt] = __builtin_amdgcn_mfma_f32_16x16x32_bf16(aQ[ks], bK, S[nt], 0, 0, 0);
      }

    float sc[4][4];
#pragma unroll
    for (int nt = 0; nt < 4; ++nt) {
      const int jg = jbase + nt * 16 + cl;
#pragma unroll
      for (int r = 0; r < 4; ++r) {
        const int i = q0 + wid * 16 + rowg * 4 + r;
        const bool v = (jg < wend) && (jg >= i - 128) && (jg <= i + 128);
        sc[nt][r] = v ? S[nt][r] * 0.125f : -1.0e30f;
      }
    }

    float alpha[4], p[4][4];
#pragma unroll
    for (int r = 0; r < 4; ++r) {
      float tm = fmaxf(fmaxf(sc[0][r], sc[1][r]), fmaxf(sc[2][r], sc[3][r]));
      tm = fmaxf(tm, __shfl_xor(tm, 1, 64));
      tm = fmaxf(tm, __shfl_xor(tm, 2, 64));
      tm = fmaxf(tm, __shfl_xor(tm, 4, 64));
      tm = fmaxf(tm, __shfl_xor(tm, 8, 64));
      const float mn = fmaxf(m_i[r], tm);
      alpha[r] = __expf(m_i[r] - mn);
      m_i[r] = mn;
      float ps = 0.f;
#pragma unroll
      for (int nt = 0; nt < 4; ++nt) { p[nt][r] = __expf(sc[nt][r] - mn); ps += p[nt][r]; }
      ps += __shfl_xor(ps, 1, 64);
      ps += __shfl_xor(ps, 2, 64);
      ps += __shfl_xor(ps, 4, 64);
      ps += __shfl_xor(ps, 8, 64);
      l_i[r] = l_i[r] * alpha[r] + ps;
    }

#pragma unroll
    for (int nt = 0; nt < 4; ++nt)
#pragma unroll
      for (int r = 0; r < 4; ++r)
        Ps[(wid * 16 + rowg * 4 + r) * 72 + nt * 16 + cl] = f2b(p[nt][r]);
    __syncthreads();

#pragma unroll
    for (int nt = 0; nt < 4; ++nt)
#pragma unroll
      for (int r = 0; r < 4; ++r) O[nt][r] *= alpha[r];
    short8 aP[2];
#pragma unroll
    for (int ks = 0; ks < 2; ++ks)
      aP[ks] = *(const short8*)&Ps[(wid * 16 + cl) * 72 + ks * 32 + kq];
#pragma unroll
    for (int nt = 0; nt < 4; ++nt)
#pragma unroll
      for (int ks = 0; ks < 2; ++ks) {
        const short8 bV = *(const short8*)&Vt[(nt * 16 + cl) * 72 + ks * 32 + kq];
        O[nt] = __builtin_amdgcn_mfma_f32_16x16x32_bf16(aP[ks], bV, O[nt], 0, 0, 0);
      }
  }

#pragma unroll
  for (int nt = 0; nt < 4; ++nt) {
    const int d = nt * 16 + cl;
#pragma unroll
    for (int r = 0; r < 4; ++r) {
      const int i = q0 + wid * 16 + rowg * 4 + r;
      ctx[(rowb + i) * 1024 + h * 64 + d] = f2b(O[nt][r] / l_i[r]);
    }
  }
}

// ---------------------------------------------------------------------------
// Residual + LayerNorm (unchanged). In-place safe per-row.
// ---------------------------------------------------------------------------
template<int AF32, int BF32, int OF32>
__global__ __launch_bounds__(256) void ln_k(
    const void* __restrict__ a, const void* __restrict__ b,
    const float* __restrict__ g, const float* __restrict__ be,
    void* __restrict__ o)
{
  __shared__ float rbuf[8];
  const int tid = threadIdx.x;
  const size_t base = (size_t)blockIdx.x * 1024;
  const int lane = tid & 63, wid = tid >> 6;

  float xv[4], s = 0.f, sq = 0.f;
#pragma unroll
  for (int t = 0; t < 4; ++t) {
    const int c = tid + t * 256;
    const float av = AF32 ? ((const float*)a)[base + c]
                          : b2f(((const unsigned short*)a)[base + c]);
    const float bv = BF32 ? ((const float*)b)[base + c]
                          : b2f(((const unsigned short*)b)[base + c]);
    const float x = av + bv;
    xv[t] = x; s += x; sq += x * x;
  }
  for (int o2 = 1; o2 < 64; o2 <<= 1) { s += __shfl_xor(s, o2, 64); sq += __shfl_xor(sq, o2, 64); }
  if (lane == 0) { rbuf[wid] = s; rbuf[wid + 4] = sq; }
  __syncthreads();
  s  = rbuf[0] + rbuf[1] + rbuf[2] + rbuf[3];
  sq = rbuf[4] + rbuf[5] + rbuf[6] + rbuf[7];
  const float mean = s * (1.0f / 1024.f);
  const float var = sq * (1.0f / 1024.f) - mean * mean;
  const float rstd = rsqrtf(var + 1e-5f);
#pragma unroll
  for (int t = 0; t < 4; ++t) {
    const int c = tid + t * 256;
    const float y = (xv[t] - mean) * rstd * g[c] + be[c];
    if (OF32) ((float*)o)[base + c] = y;
    else      ((unsigned short*)o)[base + c] = f2b(y);
  }
}

// ---------------------------------------------------------------------------
extern "C" void kernel_launch(void* const* d_in, const int* in_sizes, int n_in,
                              void* d_out, int out_size, void* d_ws, size_t ws_size,
                              hipStream_t stream)
{
  (void)in_sizes; (void)n_in; (void)out_size; (void)ws_size;
  const float* src   = (const float*)d_in[0];
  const float* w_in  = (const float*)d_in[1];
  const float* b_in  = (const float*)d_in[2];
  const float* w_out = (const float*)d_in[3];
  const float* b_out = (const float*)d_in[4];
  const float* w1    = (const float*)d_in[5];
  const float* b1    = (const float*)d_in[6];
  const float* w2    = (const float*)d_in[7];
  const float* b2    = (const float*)d_in[8];
  const float* g1    = (const float*)d_in[9];
  const float* be1   = (const float*)d_in[10];
  const float* g2    = (const float*)d_in[11];
  const float* be2   = (const float*)d_in[12];

  char* ws = (char*)d_ws;
  unsigned short* srcb  = (unsigned short*)(ws);                 // [0, 8388608)
  unsigned short* x1b   = srcb;                                  // in-place over srcb
  unsigned short* qkv   = (unsigned short*)(ws + 8388608);       // [8388608, 33554432)
  unsigned short* ctx   = (unsigned short*)(ws + 33554432);      // [33554432, 41943040)
  unsigned short* attnb = (unsigned short*)(ws + 8388608);       // reuse qkv head
  unsigned short* ff1   = (unsigned short*)(ws + 8388608);       // [8388608, 41943040)
  unsigned short* wslot = (unsigned short*)(ws + 41943040);      // [41943040, 50331648)
  float*          outf  = (float*)d_out;

  // 0) convert src -> bf16 srcb
  conv_k<<<dim3(2048), 256, 0, stream>>>(src, srcb, 4194304);
  // 1) convert in_proj_w; QKV projection -> bf16 qkv
  conv_k<<<dim3(1536), 256, 0, stream>>>(w_in, wslot, 3145728);
  gemm128<0, 0><<<dim3(24, 32), 256, 0, stream>>>(srcb, wslot, b_in, qkv, 4096, 3072, 1024);
  // 2) banded MFMA flash attention -> bf16 ctx
  attn_mfma<<<dim3(1024), 256, 0, stream>>>(qkv, ctx);
  // 3) convert out_w; output projection (gemm64) -> bf16 attnb
  conv_k<<<dim3(512), 256, 0, stream>>>(w_out, wslot, 1048576);
  gemm64<0><<<dim3(8, 64), 256, 0, stream>>>(ctx, wslot, b_out, attnb, 4096, 1024, 1024);
  // 4) LN1(srcb bf16 + attnb bf16) -> bf16 x1b (in-place over srcb)
  ln_k<0, 0, 0><<<dim3(4096), 256, 0, stream>>>(srcb, attnb, g1, be1, x1b);
  // 5) convert lin1_w; FF1 + ReLU -> bf16 ff1
  conv_k<<<dim3(2048), 256, 0, stream>>>(w1, wslot, 4194304);
  gemm128<1, 0><<<dim3(32, 32), 256, 0, stream>>>(x1b, wslot, b1, ff1, 4096, 4096, 1024);
  // 6) convert lin2_w; FF2 (gemm64) -> f32 into d_out
  conv_k<<<dim3(2048), 256, 0, stream>>>(w2, wslot, 4194304);
  gemm64<1><<<dim3(8, 64), 256, 0, stream>>>(ff1, wslot, b2, outf, 4096, 1024, 4096);
  // 7) LN2(x1b bf16 + d_out f32) -> f32 d_out (in-place, per-row safe)
  ln_k<0, 1, 1><<<dim3(4096), 256, 0, stream>>>(x1b, outf, g2, be2, outf);
}